// Round 8
// baseline (1432.824 us; speedup 1.0000x reference)
//
#include <hip/hip_runtime.h>

// ---------------------------------------------------------------------------
// KacLayer: out = x @ (W^T + M) + b, where M = A2 diag(vec) A1 (Kac walks).
// numpy default_rng(4048)/default_rng(4049): PCG64 + SeedSequence (subtractive
// mix) + 32-bit buffered Lemire ints (low u32 half first) — ALL VERIFIED r7.
// r8: (1) commuting-rotation batches (<=16, disjoint coords) built in gen via
// wave-parallel greedy -> walk gets 16-way LDS ILP (672us serial chain -> ~80us);
// (2) single-bf16 GEMM (error ~0.02 << 0.147 threshold; B scale is 1/32).
// ---------------------------------------------------------------------------

#define NSTEPS 3072
#define NCHUNK 26
#define NRAW (256 * NCHUNK)   // 6656 u64 (need 6144 + rejection slack)
#define BSLOT 16              // slots per commuting batch
#define MAXB 512              // max batches per walk (expected ~230)

typedef __attribute__((ext_vector_type(8))) short short8;
typedef __attribute__((ext_vector_type(4))) float f32x4;

struct SchedEntry { unsigned int ij; float c; float s; unsigned int pad; };

// ---------------- 128-bit PCG64 (numpy-exact) ------------------------------
struct U128 { unsigned long long lo, hi; };

__device__ __forceinline__ U128 mul128(U128 a, U128 b) {
  U128 r;
  r.lo = a.lo * b.lo;
  r.hi = __umul64hi(a.lo, b.lo) + a.lo * b.hi + a.hi * b.lo;
  return r;
}
__device__ __forceinline__ U128 add128(U128 a, U128 b) {
  U128 r; r.lo = a.lo + b.lo;
  r.hi = a.hi + b.hi + ((r.lo < a.lo) ? 1ull : 0ull);
  return r;
}
__device__ __forceinline__ U128 pcg_mult() {
  return U128{4865540595714422341ull, 2549297995355413924ull};
}
__device__ __forceinline__ U128 pcg_step(U128 st, U128 inc) {
  return add128(mul128(st, pcg_mult()), inc);
}
__device__ __forceinline__ unsigned long long pcg_out(U128 st) {
  unsigned long long x = st.hi ^ st.lo;
  unsigned int rot = (unsigned int)(st.hi >> 58);
  return (x >> rot) | (x << ((64u - rot) & 63u));
}

__device__ void pcg_seed(unsigned int seedval, U128* st, U128* inc) {
  unsigned int pool[4];
  unsigned int hc = 0x43b0d7e5u;                 // INIT_A
  auto hashmix = [&hc](unsigned int v) {
    v ^= hc; hc *= 0x931e8875u; v *= hc; v ^= v >> 16; return v;  // MULT_A
  };
  auto mixf = [](unsigned int x, unsigned int y) {
    unsigned int r = x * 0xca01f9ddu - y * 0x4973f715u;  // SUBTRACT (randutils)
    r ^= r >> 16; return r;
  };
  pool[0] = hashmix(seedval);
  pool[1] = hashmix(0u); pool[2] = hashmix(0u); pool[3] = hashmix(0u);
  for (int s = 0; s < 4; ++s)
    for (int d = 0; d < 4; ++d)
      if (s != d) pool[d] = mixf(pool[d], hashmix(pool[s]));
  unsigned int gc = 0x8b51f9ddu;                 // INIT_B
  unsigned int wv[8];
  for (int k = 0; k < 8; ++k) {
    unsigned int dv = pool[k & 3];
    dv ^= gc; gc *= 0x58f38dedu; dv *= gc; dv ^= dv >> 16;        // MULT_B
    wv[k] = dv;
  }
  unsigned long long o0 = (unsigned long long)wv[0] | ((unsigned long long)wv[1] << 32);
  unsigned long long o1 = (unsigned long long)wv[2] | ((unsigned long long)wv[3] << 32);
  unsigned long long o2 = (unsigned long long)wv[4] | ((unsigned long long)wv[5] << 32);
  unsigned long long o3 = (unsigned long long)wv[6] | ((unsigned long long)wv[7] << 32);
  U128 initstate = { o1, o0 };
  U128 initseq   = { o3, o2 };
  U128 icc; icc.lo = (initseq.lo << 1) | 1ull;
  icc.hi = (initseq.hi << 1) | (initseq.lo >> 63);
  *inc = icc;
  U128 s0 = {0ull, 0ull};
  s0 = pcg_step(s0, icc);
  s0 = add128(s0, initstate);
  s0 = pcg_step(s0, icc);
  *st = s0;
}

__device__ U128 pcg_advance(U128 st, U128 inc, unsigned long long delta) {
  U128 am = {1ull, 0ull}, ap = {0ull, 0ull};
  U128 cm = pcg_mult(), cp = inc;
  while (delta) {
    if (delta & 1ull) {
      am = mul128(am, cm);
      ap = add128(mul128(ap, cm), cp);
    }
    cp = mul128(add128(cm, U128{1ull, 0ull}), cp);
    cm = mul128(cm, cm);
    delta >>= 1;
  }
  return add128(mul128(st, am), ap);
}

__device__ __forceinline__ double first_draw(unsigned int seed) {
  U128 st, inc;
  pcg_seed(seed, &st, &inc);
  st = pcg_step(st, inc);
  return (double)(pcg_out(st) >> 11) * (1.0 / 9007199254740992.0);
}

__device__ __forceinline__ unsigned short f32_to_bf16(float f) {
  unsigned int u = __builtin_bit_cast(unsigned int, f);
  unsigned int r = u + 0x7fffu + ((u >> 16) & 1u);
  return (unsigned short)(r >> 16);
}

// ---------------- Kernel 1: schedule gen + commuting-batch build ----------
__global__ __launch_bounds__(256) void gen_sched_kernel(SchedEntry* __restrict__ bs0,
                                                        SchedEntry* __restrict__ bs1,
                                                        int* __restrict__ hdr,
                                                        float* __restrict__ diag) {
  __shared__ unsigned long long raw[NRAW];          // 53 KB
  __shared__ unsigned int s_ij[NSTEPS];             // 12 KB
  __shared__ unsigned short s_slot[NSTEPS];         // 6 KB
  __shared__ int s_rej;
  __shared__ int s_p64;
  const int w = blockIdx.x;     // walk: seed 4048 + w
  const int t = threadIdx.x;
  SchedEntry* bs = w ? bs1 : bs0;

  if (w == 0 && t == 0) {
    int m1 = first_draw(42u)    != 0.7739560485559633;
    int m2 = first_draw(0u)     != 0.6369616873214543;
    int m3 = first_draw(12345u) != 0.22733602246716966;
    if (m1 + m2 + m3 >= 2)
      diag[0] = 3.0e8f + (float)(m1 + 2 * m2 + 4 * m3) * 3.0e7f;
  }

  U128 st, inc;
  pcg_seed(4048u + (unsigned int)w, &st, &inc);
  U128 mine = pcg_advance(st, inc, (unsigned long long)t * NCHUNK);
  for (int q = 0; q < NCHUNK; ++q) {
    mine = pcg_step(mine, inc);
    raw[t * NCHUNK + q] = pcg_out(mine);
  }
  if (t == 0) s_rej = 0;
  __syncthreads();

  // u32 draw m: LOW half of u64 first, then HIGH (pcg64_next32 buffering)
  auto u32at = [&](int m) -> unsigned int {
    unsigned long long v = raw[m >> 1];
    return (m & 1) ? (unsigned int)(v >> 32) : (unsigned int)v;
  };

  for (int k = t; k < NSTEPS; k += 256) {
    unsigned long long m = (unsigned long long)u32at(NSTEPS + k) * 1023ull;
    if ((unsigned int)m < 4u) atomicAdd(&s_rej, 1);
  }
  __syncthreads();

  if (s_rej == 0) {
    for (int k = t; k < NSTEPS; k += 256) {
      unsigned int iv = u32at(k) >> 22;                 // (u32*1024)>>32
      unsigned long long m = (unsigned long long)u32at(NSTEPS + k) * 1023ull;
      unsigned int off = 1u + (unsigned int)(m >> 32);
      unsigned int jv = (iv + off) & 1023u;
      s_ij[k] = (iv << 16) | jv;
    }
    if (t == 0) s_p64 = NSTEPS;        // 6144 u32 consumed -> u64 idx 3072
  } else if (t == 0) {
    // exact sequential replay with rejections (P ~ 3e-6 per walk)
    int p = 0;
    for (int k = 0; k < NSTEPS; ++k) s_ij[k] = (u32at(p++) >> 22) << 16;
    for (int k = 0; k < NSTEPS; ++k) {
      unsigned long long m = (unsigned long long)u32at(p++) * 1023ull;
      unsigned int lo = (unsigned int)m;
      if (lo < 1023u) {
        while (lo < 4u) { m = (unsigned long long)u32at(p++) * 1023ull; lo = (unsigned int)m; }
      }
      unsigned int off = 1u + (unsigned int)(m >> 32);
      unsigned int iv = s_ij[k] >> 16;
      s_ij[k] = (iv << 16) | ((iv + off) & 1023u);
    }
    s_p64 = (p + 1) >> 1;
  }
  __syncthreads();

  // --- wave-parallel greedy batching: pack steps into commuting batches ----
  // Lane q holds the q-th touched coord of the current batch; conflict via
  // ballot. Uniform scalars (nb,pos,ntouch) maintained identically per lane.
  if (t < 64) {
    const int lane = t;
    int mycoord = -1;
    int nb = 0, pos = 0, ntouch = 0;
    for (int k0 = 0; k0 < NSTEPS; k0 += 64) {
      unsigned int chunk = s_ij[k0 + lane];
      for (int q = 0; q < 64; ++q) {
        unsigned int cand = __shfl(chunk, q);
        int i = (int)(cand >> 16), j = (int)(cand & 0xffffu);
        bool hit = (lane < ntouch) && (mycoord == i || mycoord == j);
        bool close = (__ballot(hit) != 0ull) || (pos == BSLOT);
        if (close) {
          if (lane >= pos && lane < BSLOT && nb < MAXB) {
            bs[nb * BSLOT + lane].ij = (1024u << 16) | 1024u;  // no-op pad
            bs[nb * BSLOT + lane].c = 1.0f;
            bs[nb * BSLOT + lane].s = 0.0f;
          }
          ++nb; pos = 0; ntouch = 0;
        }
        if (lane == ntouch) mycoord = i;
        if (lane == ntouch + 1) mycoord = j;
        ntouch += 2;
        if (lane == 0) s_slot[k0 + q] = (unsigned short)(nb * BSLOT + pos);
        ++pos;
      }
    }
    // close final batch
    if (lane >= pos && lane < BSLOT && nb < MAXB) {
      bs[nb * BSLOT + lane].ij = (1024u << 16) | 1024u;
      bs[nb * BSLOT + lane].c = 1.0f;
      bs[nb * BSLOT + lane].s = 0.0f;
    }
    ++nb;
    if (lane == 0) {
      hdr[w] = (nb <= MAXB) ? nb : MAXB;
      if (nb > MAXB) diag[3] = 6.0e8f;   // batch overflow (practically impossible)
    }
  }
  __syncthreads();

  // --- emit: angles + scatter entries to their batch slots -----------------
  const int base = s_p64;
  for (int k = t; k < NSTEPS; k += 256) {
    unsigned long long v = raw[base + k];
    double d = (double)(v >> 11) * (1.0 / 9007199254740992.0);  // next_double
    double ang = d * 6.283185307179586;
    int slot = s_slot[k];
    if (slot < MAXB * BSLOT) {
      bs[slot].ij = s_ij[k];
      bs[slot].c = (float)cos(ang);
      bs[slot].s = (float)sin(ang);
    }
  }
}

// ---------------- Kernel 2: batched Kac walk on identity + combine ---------
// L[1025 coords][16 rows]; coord 1024 = scratch for pad no-ops. Lane r owns
// row r. Per batch: 32 independent ds_reads -> 1 wait -> FMAs -> 32 writes.
__device__ void walk_phase(const SchedEntry* __restrict__ bsched, int nb,
                           float* __restrict__ L, int r) {
  uint4 cur[BSLOT], nxt[BSLOT];
  const uint4* sp = (const uint4*)bsched;
  #pragma unroll
  for (int q = 0; q < BSLOT; ++q) cur[q] = sp[q];
  for (int b = 0; b < nb; ++b) {
    if (b + 1 < nb) {
      #pragma unroll
      for (int q = 0; q < BSLOT; ++q) nxt[q] = sp[(b + 1) * BSLOT + q];
    }
    float xi[BSLOT], xj[BSLOT];
    #pragma unroll
    for (int q = 0; q < BSLOT; ++q) {
      unsigned int ij = cur[q].x;
      int i = (int)(ij >> 16), j = (int)(ij & 0xffffu);
      xi[q] = L[i * 16 + r];
      xj[q] = L[j * 16 + r];
    }
    #pragma unroll
    for (int q = 0; q < BSLOT; ++q) {
      unsigned int ij = cur[q].x;
      int i = (int)(ij >> 16), j = (int)(ij & 0xffffu);
      float c = __uint_as_float(cur[q].y);
      float s = __uint_as_float(cur[q].z);
      L[i * 16 + r] = fmaf(c, xi[q], -s * xj[q]);
      L[j * 16 + r] = fmaf(s, xi[q],  c * xj[q]);
    }
    #pragma unroll
    for (int q = 0; q < BSLOT; ++q) cur[q] = nxt[q];
  }
}

__global__ __launch_bounds__(256) void walk_kernel(const SchedEntry* __restrict__ bs0,
                                                   const SchedEntry* __restrict__ bs1,
                                                   const int* __restrict__ hdr,
                                                   const float* __restrict__ W,
                                                   const float* __restrict__ vec,
                                                   unsigned short* __restrict__ Bh,
                                                   float* __restrict__ diag) {
  __shared__ float L[1025 * 16];   // 65.6 KB (coord 1024 = pad scratch)
  const int b = blockIdx.x;        // 0..63
  const int t = threadIdx.x;
  const int d0 = b * 16;
  const int nb0 = hdr[0], nb1 = hdr[1];
  for (int idx = t; idx < 1025 * 16; idx += 256) {
    int c = idx >> 4, r = idx & 15;
    L[idx] = (c == d0 + r) ? 1.0f : 0.0f;
  }
  __syncthreads();
  if (t < 16) walk_phase(bs0, nb0, L, t);
  __syncthreads();
  {  // Givens chains preserve unit norms
    bool bad = false;
    if (t < 16) {
      float ss = 0.0f;
      for (int c = 0; c < 1024; ++c) { float v = L[c * 16 + t]; ss += v * v; }
      bad = fabsf(ss - 1.0f) > 2.0e-3f;
    }
    unsigned long long bm = __ballot(bad);
    if (b == 0 && t == 0 && bm) diag[1] = 2.0e7f;
  }
  __syncthreads();
  for (int idx = t; idx < 1024 * 16; idx += 256) L[idx] *= vec[idx >> 4];
  __syncthreads();
  if (t < 16) walk_phase(bs1, nb1, L, t);
  __syncthreads();
  // B[e][d0+dl] = W[e][d0+dl] + M[e][d0+dl];  M[e][d0+dl] = L[e*16+dl]
  const int dl = t & 15;
  const int eb = t >> 4;
  for (int p = 0; p < 64; ++p) {
    int e = eb + p * 16;
    Bh[e * 1024 + d0 + dl] = f32_to_bf16(W[e * 1024 + d0 + dl] + L[e * 16 + dl]);
  }
}

// ---------------- Kernel 3: bf16 GEMM out = x @ B^T + b --------------------
__device__ __forceinline__ int swz(int row, int colbyte) {
  return row * 128 + (colbyte ^ ((row & 7) << 4));
}

__global__ __launch_bounds__(256) void gemm_kernel(const float* __restrict__ x,
                                                   const unsigned short* __restrict__ Bhg,
                                                   const float* __restrict__ bvec,
                                                   const float* __restrict__ diag,
                                                   float* __restrict__ out) {
  __shared__ unsigned short Ash[128 * 64];   // 16 KB, swizzled
  __shared__ unsigned short Bsh[128 * 64];
  const int t = threadIdx.x;
  const int bm = blockIdx.x & 255;           // panel-major for XCD L2 locality
  const int bn = blockIdx.x >> 8;
  const int m0 = bm * 128, n0 = bn * 128;
  const int l = t & 63, w = t >> 6;
  const int wr = w >> 1, wc = w & 1;
  const int lr = l & 15, lk = l >> 4;
  const int arb = t >> 4, akb = (t & 15) << 3;
  const int brb = t >> 3, bkb = (t & 7) << 4;

  f32x4 acc[4][4] = {};
  float4 ra[8];
  uint4 rb[4];

  #pragma unroll
  for (int p = 0; p < 8; ++p)
    ra[p] = *(const float4*)&x[(size_t)(m0 + arb + p * 16) * 1024 + (akb >> 1)];
  #pragma unroll
  for (int p = 0; p < 4; ++p)
    rb[p] = *(const uint4*)&Bhg[(size_t)(n0 + brb + p * 32) * 1024 + (bkb >> 1)];

  for (int kt = 0; kt < 16; ++kt) {
    #pragma unroll
    for (int p = 0; p < 8; ++p) {
      ushort4 hv;
      hv.x = f32_to_bf16(ra[p].x); hv.y = f32_to_bf16(ra[p].y);
      hv.z = f32_to_bf16(ra[p].z); hv.w = f32_to_bf16(ra[p].w);
      *(ushort4*)((char*)Ash + swz(arb + p * 16, akb)) = hv;
    }
    #pragma unroll
    for (int p = 0; p < 4; ++p)
      *(uint4*)((char*)Bsh + swz(brb + p * 32, bkb)) = rb[p];
    __syncthreads();

    if (kt + 1 < 16) {
      const int k0 = (kt + 1) * 64;
      #pragma unroll
      for (int p = 0; p < 8; ++p)
        ra[p] = *(const float4*)&x[(size_t)(m0 + arb + p * 16) * 1024 + k0 + (akb >> 1)];
      #pragma unroll
      for (int p = 0; p < 4; ++p)
        rb[p] = *(const uint4*)&Bhg[(size_t)(n0 + brb + p * 32) * 1024 + k0 + (bkb >> 1)];
    }

    #pragma unroll
    for (int kk = 0; kk < 64; kk += 32) {
      short8 af[4], bf[4];
      const int cb = kk * 2 + lk * 16;
      #pragma unroll
      for (int m4 = 0; m4 < 4; ++m4)
        af[m4] = *(const short8*)((const char*)Ash + swz(wr * 64 + m4 * 16 + lr, cb));
      #pragma unroll
      for (int n4 = 0; n4 < 4; ++n4)
        bf[n4] = *(const short8*)((const char*)Bsh + swz(wc * 64 + n4 * 16 + lr, cb));
      #pragma unroll
      for (int m4 = 0; m4 < 4; ++m4)
        #pragma unroll
        for (int n4 = 0; n4 < 4; ++n4)
          acc[m4][n4] = __builtin_amdgcn_mfma_f32_16x16x32_bf16(af[m4], bf[n4], acc[m4][n4], 0, 0, 0);
    }
    __syncthreads();
  }

  #pragma unroll
  for (int n4 = 0; n4 < 4; ++n4) {
    const int col = n0 + wc * 64 + n4 * 16 + lr;
    const float bias = bvec[col];
    #pragma unroll
    for (int m4 = 0; m4 < 4; ++m4) {
      const int row = m0 + wr * 64 + m4 * 16 + lk * 4;
      #pragma unroll
      for (int q = 0; q < 4; ++q)
        out[(size_t)(row + q) * 1024 + col] = acc[m4][n4][q] + bias;
    }
  }

  if (blockIdx.x == 0 && t == 0) {
    float dg = diag[0] + diag[1] + diag[3];
    if (dg != 0.0f) out[0] += dg;
  }
}

__global__ void signal_kernel(float* out, float val) { out[0] = val; }

// ---------------------------------------------------------------------------
extern "C" void kernel_launch(void* const* d_in, const int* in_sizes, int n_in,
                              void* d_out, int out_size, void* d_ws, size_t ws_size,
                              hipStream_t stream) {
  const float* x    = (const float*)d_in[0];
  const float* W    = (const float*)d_in[1];
  const float* bvec = (const float*)d_in[2];
  const float* vec  = (const float*)d_in[3];
  float* out = (float*)d_out;

  const size_t MB = 1024 * 1024;
  // layout: diag @0 (64B floats), hdr @64 (ints), bs0 @4096 (128KB),
  //         bs1 @135168 (128KB), Bh @1MB (2MB)
  const size_t need = MB + 2 * MB;
  if (ws_size < need) {
    signal_kernel<<<1, 1, 0, stream>>>(out, 4.0e8f + (float)(ws_size >> 20) * 1000.0f);
    return;
  }
  float* diag = (float*)d_ws;
  int* hdr = (int*)((char*)d_ws + 64);
  SchedEntry* bs0 = (SchedEntry*)((char*)d_ws + 4096);
  SchedEntry* bs1 = (SchedEntry*)((char*)d_ws + 4096 + MAXB * BSLOT * sizeof(SchedEntry));
  unsigned short* Bh = (unsigned short*)((char*)d_ws + MB);

  hipMemsetAsync(diag, 0, 64, stream);
  gen_sched_kernel<<<2, 256, 0, stream>>>(bs0, bs1, hdr, diag);
  walk_kernel<<<64, 256, 0, stream>>>(bs0, bs1, hdr, W, vec, Bh, diag);
  gemm_kernel<<<2048, 256, 0, stream>>>(x, Bh, bvec, diag, out);
}

// Round 9
// 793.050 us; speedup vs baseline: 1.8067x; 1.8067x over previous
//
#include <hip/hip_runtime.h>

// ---------------------------------------------------------------------------
// KacLayer: out = x @ (W^T + M) + b, where M = A2 diag(vec) A1 (Kac walks).
// numpy default_rng(4048)/default_rng(4049): PCG64 + SeedSequence (subtractive
// mix) + 32-bit buffered Lemire ints (low u32 half first) — verified r7.
// r9: walk processes fixed GROUPS of 8 rotations: pre-read all 16 operands
// (one lgkmcnt drain per group, not per step), conflict steps (precomputed
// 8-bit mask in gen, ~10% of groups) lazily re-read. Schedule staged in LDS.
// Single-bf16 GEMM (validated r8: absmax 0.03125 unchanged vs split).
// ---------------------------------------------------------------------------

#define NSTEPS 3072
#define NCHUNK 26
#define NRAW (256 * NCHUNK)   // 6656 u64 (need 6144 + rejection slack)
#define GRP 8
#define NGROUP (NSTEPS / GRP) // 384

typedef __attribute__((ext_vector_type(8))) short short8;
typedef __attribute__((ext_vector_type(4))) float f32x4;

struct SchedEntry { unsigned int ij; float c; float s; unsigned int pad; };

// ---------------- 128-bit PCG64 (numpy-exact) ------------------------------
struct U128 { unsigned long long lo, hi; };

__device__ __forceinline__ U128 mul128(U128 a, U128 b) {
  U128 r;
  r.lo = a.lo * b.lo;
  r.hi = __umul64hi(a.lo, b.lo) + a.lo * b.hi + a.hi * b.lo;
  return r;
}
__device__ __forceinline__ U128 add128(U128 a, U128 b) {
  U128 r; r.lo = a.lo + b.lo;
  r.hi = a.hi + b.hi + ((r.lo < a.lo) ? 1ull : 0ull);
  return r;
}
__device__ __forceinline__ U128 pcg_mult() {
  return U128{4865540595714422341ull, 2549297995355413924ull};
}
__device__ __forceinline__ U128 pcg_step(U128 st, U128 inc) {
  return add128(mul128(st, pcg_mult()), inc);
}
__device__ __forceinline__ unsigned long long pcg_out(U128 st) {
  unsigned long long x = st.hi ^ st.lo;
  unsigned int rot = (unsigned int)(st.hi >> 58);
  return (x >> rot) | (x << ((64u - rot) & 63u));
}

__device__ void pcg_seed(unsigned int seedval, U128* st, U128* inc) {
  unsigned int pool[4];
  unsigned int hc = 0x43b0d7e5u;                 // INIT_A
  auto hashmix = [&hc](unsigned int v) {
    v ^= hc; hc *= 0x931e8875u; v *= hc; v ^= v >> 16; return v;  // MULT_A
  };
  auto mixf = [](unsigned int x, unsigned int y) {
    unsigned int r = x * 0xca01f9ddu - y * 0x4973f715u;  // SUBTRACT (randutils)
    r ^= r >> 16; return r;
  };
  pool[0] = hashmix(seedval);
  pool[1] = hashmix(0u); pool[2] = hashmix(0u); pool[3] = hashmix(0u);
  for (int s = 0; s < 4; ++s)
    for (int d = 0; d < 4; ++d)
      if (s != d) pool[d] = mixf(pool[d], hashmix(pool[s]));
  unsigned int gc = 0x8b51f9ddu;                 // INIT_B
  unsigned int wv[8];
  for (int k = 0; k < 8; ++k) {
    unsigned int dv = pool[k & 3];
    dv ^= gc; gc *= 0x58f38dedu; dv *= gc; dv ^= dv >> 16;        // MULT_B
    wv[k] = dv;
  }
  unsigned long long o0 = (unsigned long long)wv[0] | ((unsigned long long)wv[1] << 32);
  unsigned long long o1 = (unsigned long long)wv[2] | ((unsigned long long)wv[3] << 32);
  unsigned long long o2 = (unsigned long long)wv[4] | ((unsigned long long)wv[5] << 32);
  unsigned long long o3 = (unsigned long long)wv[6] | ((unsigned long long)wv[7] << 32);
  U128 initstate = { o1, o0 };
  U128 initseq   = { o3, o2 };
  U128 icc; icc.lo = (initseq.lo << 1) | 1ull;
  icc.hi = (initseq.hi << 1) | (initseq.lo >> 63);
  *inc = icc;
  U128 s0 = {0ull, 0ull};
  s0 = pcg_step(s0, icc);
  s0 = add128(s0, initstate);
  s0 = pcg_step(s0, icc);
  *st = s0;
}

__device__ U128 pcg_advance(U128 st, U128 inc, unsigned long long delta) {
  U128 am = {1ull, 0ull}, ap = {0ull, 0ull};
  U128 cm = pcg_mult(), cp = inc;
  while (delta) {
    if (delta & 1ull) {
      am = mul128(am, cm);
      ap = add128(mul128(ap, cm), cp);
    }
    cp = mul128(add128(cm, U128{1ull, 0ull}), cp);
    cm = mul128(cm, cm);
    delta >>= 1;
  }
  return add128(mul128(st, am), ap);
}

__device__ __forceinline__ double first_draw(unsigned int seed) {
  U128 st, inc;
  pcg_seed(seed, &st, &inc);
  st = pcg_step(st, inc);
  return (double)(pcg_out(st) >> 11) * (1.0 / 9007199254740992.0);
}

__device__ __forceinline__ unsigned short f32_to_bf16(float f) {
  unsigned int u = __builtin_bit_cast(unsigned int, f);
  unsigned int r = u + 0x7fffu + ((u >> 16) & 1u);
  return (unsigned short)(r >> 16);
}

// ---------------- Kernel 1: schedule gen + group conflict masks ------------
__global__ __launch_bounds__(256) void gen_sched_kernel(SchedEntry* __restrict__ sched,
                                                        unsigned char* __restrict__ masks,
                                                        float* __restrict__ diag) {
  __shared__ unsigned long long raw[NRAW];          // 53 KB
  __shared__ unsigned int s_ij[NSTEPS];             // 12 KB
  __shared__ int s_rej;
  __shared__ int s_p64;
  const int w = blockIdx.x;     // walk: seed 4048 + w
  const int t = threadIdx.x;

  if (w == 0 && t == 0) {
    int m1 = first_draw(42u)    != 0.7739560485559633;
    int m2 = first_draw(0u)     != 0.6369616873214543;
    int m3 = first_draw(12345u) != 0.22733602246716966;
    if (m1 + m2 + m3 >= 2)
      diag[0] = 3.0e8f + (float)(m1 + 2 * m2 + 4 * m3) * 3.0e7f;
  }

  U128 st, inc;
  pcg_seed(4048u + (unsigned int)w, &st, &inc);
  U128 mine = pcg_advance(st, inc, (unsigned long long)t * NCHUNK);
  for (int q = 0; q < NCHUNK; ++q) {
    mine = pcg_step(mine, inc);
    raw[t * NCHUNK + q] = pcg_out(mine);
  }
  if (t == 0) s_rej = 0;
  __syncthreads();

  // u32 draw m: LOW half of u64 first, then HIGH (pcg64_next32 buffering)
  auto u32at = [&](int m) -> unsigned int {
    unsigned long long v = raw[m >> 1];
    return (m & 1) ? (unsigned int)(v >> 32) : (unsigned int)v;
  };

  for (int k = t; k < NSTEPS; k += 256) {
    unsigned long long m = (unsigned long long)u32at(NSTEPS + k) * 1023ull;
    if ((unsigned int)m < 4u) atomicAdd(&s_rej, 1);
  }
  __syncthreads();

  if (s_rej == 0) {
    for (int k = t; k < NSTEPS; k += 256) {
      unsigned int iv = u32at(k) >> 22;                 // (u32*1024)>>32
      unsigned long long m = (unsigned long long)u32at(NSTEPS + k) * 1023ull;
      unsigned int off = 1u + (unsigned int)(m >> 32);
      unsigned int jv = (iv + off) & 1023u;
      s_ij[k] = (iv << 16) | jv;
    }
    if (t == 0) s_p64 = NSTEPS;        // 6144 u32 consumed -> u64 idx 3072
  } else if (t == 0) {
    // exact sequential replay with rejections (P ~ 3e-6 per walk)
    int p = 0;
    for (int k = 0; k < NSTEPS; ++k) s_ij[k] = (u32at(p++) >> 22) << 16;
    for (int k = 0; k < NSTEPS; ++k) {
      unsigned long long m = (unsigned long long)u32at(p++) * 1023ull;
      unsigned int lo = (unsigned int)m;
      if (lo < 1023u) {
        while (lo < 4u) { m = (unsigned long long)u32at(p++) * 1023ull; lo = (unsigned int)m; }
      }
      unsigned int off = 1u + (unsigned int)(m >> 32);
      unsigned int iv = s_ij[k] >> 16;
      s_ij[k] = (iv << 16) | ((iv + off) & 1023u);
    }
    s_p64 = (p + 1) >> 1;
  }
  __syncthreads();

  // emit schedule (ij + angles)
  const int base = s_p64;
  for (int k = t; k < NSTEPS; k += 256) {
    unsigned long long v = raw[base + k];
    double d = (double)(v >> 11) * (1.0 / 9007199254740992.0);  // next_double
    double ang = d * 6.283185307179586;
    sched[w * NSTEPS + k].ij = s_ij[k];
    sched[w * NSTEPS + k].c = (float)cos(ang);
    sched[w * NSTEPS + k].s = (float)sin(ang);
    sched[w * NSTEPS + k].pad = 0u;
  }

  // group conflict masks: bit q set iff step q shares a coord with any p<q
  for (int g = t; g < NGROUP; g += 256) {
    unsigned int msk = 0;
    unsigned int iv[GRP], jv[GRP];
    #pragma unroll
    for (int q = 0; q < GRP; ++q) {
      unsigned int e = s_ij[g * GRP + q];
      iv[q] = e >> 16; jv[q] = e & 0xffffu;
    }
    #pragma unroll
    for (int q = 1; q < GRP; ++q) {
      bool hit = false;
      #pragma unroll
      for (int p = 0; p < GRP; ++p) {
        if (p < q)
          hit = hit || (iv[q] == iv[p]) || (iv[q] == jv[p]) ||
                       (jv[q] == iv[p]) || (jv[q] == jv[p]);
      }
      if (hit) msk |= (1u << q);
    }
    masks[w * NGROUP + g] = (unsigned char)msk;
  }
}

// ---------------- Kernel 2: grouped Kac walk on identity + combine ---------
// L[1024 coords][16 rows]; lane r owns row r (reads+writes both coords).
// Per group of 8: 16 pre-reads -> one wait -> 8 rotations (conflicted steps
// re-read lazily; mask is wave-uniform so the branch is scalar).
__device__ void walk_groups(const uint4* __restrict__ SG,
                            const unsigned char* __restrict__ SM,
                            float* __restrict__ L, int r) {
  for (int g = 0; g < NGROUP; ++g) {
    unsigned int msk = SM[g];
    int ii[GRP], jj[GRP];
    float cc[GRP], ss[GRP], xi[GRP], xj[GRP];
    #pragma unroll
    for (int q = 0; q < GRP; ++q) {
      uint4 e = SG[g * GRP + q];
      ii[q] = (int)(e.x >> 16); jj[q] = (int)(e.x & 0xffffu);
      cc[q] = __uint_as_float(e.y); ss[q] = __uint_as_float(e.z);
      xi[q] = L[ii[q] * 16 + r];
      xj[q] = L[jj[q] * 16 + r];
    }
    #pragma unroll
    for (int q = 0; q < GRP; ++q) {
      float a = xi[q], b = xj[q];
      if (msk & (1u << q)) {           // uniform branch, ~10% of groups
        a = L[ii[q] * 16 + r];
        b = L[jj[q] * 16 + r];
      }
      L[ii[q] * 16 + r] = fmaf(cc[q], a, -ss[q] * b);
      L[jj[q] * 16 + r] = fmaf(ss[q], a,  cc[q] * b);
    }
  }
}

__global__ __launch_bounds__(256) void walk_kernel(const SchedEntry* __restrict__ sched,
                                                   const unsigned char* __restrict__ masks,
                                                   const float* __restrict__ W,
                                                   const float* __restrict__ vec,
                                                   unsigned short* __restrict__ Bh,
                                                   float* __restrict__ diag) {
  __shared__ float L[1024 * 16];        // 64 KB
  __shared__ uint4 SG[NSTEPS];          // 48 KB (one phase's schedule)
  __shared__ unsigned char SM[NGROUP];  // 384 B
  const int b = blockIdx.x;             // 0..63
  const int t = threadIdx.x;
  const int d0 = b * 16;

  // stage phase-0 schedule + masks
  for (int idx = t; idx < NSTEPS; idx += 256)
    SG[idx] = ((const uint4*)sched)[idx];
  for (int g = t; g < NGROUP; g += 256) SM[g] = masks[g];
  for (int idx = t; idx < 1024 * 16; idx += 256) {
    int c = idx >> 4, r = idx & 15;
    L[idx] = (c == d0 + r) ? 1.0f : 0.0f;
  }
  __syncthreads();
  if (t < 16) walk_groups(SG, SM, L, t);
  __syncthreads();
  {  // Givens chains preserve unit norms
    bool bad = false;
    if (t < 16) {
      float ss = 0.0f;
      for (int c = 0; c < 1024; ++c) { float v = L[c * 16 + t]; ss += v * v; }
      bad = fabsf(ss - 1.0f) > 2.0e-3f;
    }
    unsigned long long bm = __ballot(bad);
    if (b == 0 && t == 0 && bm) diag[1] = 2.0e7f;
  }
  __syncthreads();
  for (int idx = t; idx < 1024 * 16; idx += 256) L[idx] *= vec[idx >> 4];
  // stage phase-1 schedule + masks (SG free after phase-0 walk)
  for (int idx = t; idx < NSTEPS; idx += 256)
    SG[idx] = ((const uint4*)sched)[NSTEPS + idx];
  for (int g = t; g < NGROUP; g += 256) SM[g] = masks[NGROUP + g];
  __syncthreads();
  if (t < 16) walk_groups(SG, SM, L, t);
  __syncthreads();
  // B[e][d0+dl] = W[e][d0+dl] + M[e][d0+dl];  M[e][d0+dl] = L[e*16+dl]
  const int dl = t & 15;
  const int eb = t >> 4;
  for (int p = 0; p < 64; ++p) {
    int e = eb + p * 16;
    Bh[e * 1024 + d0 + dl] = f32_to_bf16(W[e * 1024 + d0 + dl] + L[e * 16 + dl]);
  }
}

// ---------------- Kernel 3: bf16 GEMM out = x @ B^T + b --------------------
__device__ __forceinline__ int swz(int row, int colbyte) {
  return row * 128 + (colbyte ^ ((row & 7) << 4));
}

__global__ __launch_bounds__(256) void gemm_kernel(const float* __restrict__ x,
                                                   const unsigned short* __restrict__ Bhg,
                                                   const float* __restrict__ bvec,
                                                   const float* __restrict__ diag,
                                                   float* __restrict__ out) {
  __shared__ unsigned short Ash[128 * 64];   // 16 KB, swizzled
  __shared__ unsigned short Bsh[128 * 64];
  const int t = threadIdx.x;
  const int bm = blockIdx.x & 255;           // panel-major for XCD L2 locality
  const int bn = blockIdx.x >> 8;
  const int m0 = bm * 128, n0 = bn * 128;
  const int l = t & 63, w = t >> 6;
  const int wr = w >> 1, wc = w & 1;
  const int lr = l & 15, lk = l >> 4;
  const int arb = t >> 4, akb = (t & 15) << 3;
  const int brb = t >> 3, bkb = (t & 7) << 4;

  f32x4 acc[4][4] = {};
  float4 ra[8];
  uint4 rb[4];

  #pragma unroll
  for (int p = 0; p < 8; ++p)
    ra[p] = *(const float4*)&x[(size_t)(m0 + arb + p * 16) * 1024 + (akb >> 1)];
  #pragma unroll
  for (int p = 0; p < 4; ++p)
    rb[p] = *(const uint4*)&Bhg[(size_t)(n0 + brb + p * 32) * 1024 + (bkb >> 1)];

  for (int kt = 0; kt < 16; ++kt) {
    #pragma unroll
    for (int p = 0; p < 8; ++p) {
      ushort4 hv;
      hv.x = f32_to_bf16(ra[p].x); hv.y = f32_to_bf16(ra[p].y);
      hv.z = f32_to_bf16(ra[p].z); hv.w = f32_to_bf16(ra[p].w);
      *(ushort4*)((char*)Ash + swz(arb + p * 16, akb)) = hv;
    }
    #pragma unroll
    for (int p = 0; p < 4; ++p)
      *(uint4*)((char*)Bsh + swz(brb + p * 32, bkb)) = rb[p];
    __syncthreads();

    if (kt + 1 < 16) {
      const int k0 = (kt + 1) * 64;
      #pragma unroll
      for (int p = 0; p < 8; ++p)
        ra[p] = *(const float4*)&x[(size_t)(m0 + arb + p * 16) * 1024 + k0 + (akb >> 1)];
      #pragma unroll
      for (int p = 0; p < 4; ++p)
        rb[p] = *(const uint4*)&Bhg[(size_t)(n0 + brb + p * 32) * 1024 + k0 + (bkb >> 1)];
    }

    #pragma unroll
    for (int kk = 0; kk < 64; kk += 32) {
      short8 af[4], bf[4];
      const int cb = kk * 2 + lk * 16;
      #pragma unroll
      for (int m4 = 0; m4 < 4; ++m4)
        af[m4] = *(const short8*)((const char*)Ash + swz(wr * 64 + m4 * 16 + lr, cb));
      #pragma unroll
      for (int n4 = 0; n4 < 4; ++n4)
        bf[n4] = *(const short8*)((const char*)Bsh + swz(wc * 64 + n4 * 16 + lr, cb));
      #pragma unroll
      for (int m4 = 0; m4 < 4; ++m4)
        #pragma unroll
        for (int n4 = 0; n4 < 4; ++n4)
          acc[m4][n4] = __builtin_amdgcn_mfma_f32_16x16x32_bf16(af[m4], bf[n4], acc[m4][n4], 0, 0, 0);
    }
    __syncthreads();
  }

  #pragma unroll
  for (int n4 = 0; n4 < 4; ++n4) {
    const int col = n0 + wc * 64 + n4 * 16 + lr;
    const float bias = bvec[col];
    #pragma unroll
    for (int m4 = 0; m4 < 4; ++m4) {
      const int row = m0 + wr * 64 + m4 * 16 + lk * 4;
      #pragma unroll
      for (int q = 0; q < 4; ++q)
        out[(size_t)(row + q) * 1024 + col] = acc[m4][n4][q] + bias;
    }
  }

  if (blockIdx.x == 0 && t == 0) {
    float dg = diag[0] + diag[1];
    if (dg != 0.0f) out[0] += dg;
  }
}

__global__ void signal_kernel(float* out, float val) { out[0] = val; }

// ---------------------------------------------------------------------------
extern "C" void kernel_launch(void* const* d_in, const int* in_sizes, int n_in,
                              void* d_out, int out_size, void* d_ws, size_t ws_size,
                              hipStream_t stream) {
  const float* x    = (const float*)d_in[0];
  const float* W    = (const float*)d_in[1];
  const float* bvec = (const float*)d_in[2];
  const float* vec  = (const float*)d_in[3];
  float* out = (float*)d_out;

  const size_t MB = 1024 * 1024;
  // layout: diag @0 (64B), sched @4096 (96KB), masks @102400 (768B), Bh @1MB (2MB)
  const size_t need = 3 * MB;
  if (ws_size < need) {
    signal_kernel<<<1, 1, 0, stream>>>(out, 4.0e8f + (float)(ws_size >> 20) * 1000.0f);
    return;
  }
  float* diag = (float*)d_ws;
  SchedEntry* sched = (SchedEntry*)((char*)d_ws + 4096);
  unsigned char* masks = (unsigned char*)((char*)d_ws + 102400);
  unsigned short* Bh = (unsigned short*)((char*)d_ws + MB);

  hipMemsetAsync(diag, 0, 64, stream);
  gen_sched_kernel<<<2, 256, 0, stream>>>(sched, masks, diag);
  walk_kernel<<<64, 256, 0, stream>>>(sched, masks, W, vec, Bh, diag);
  gemm_kernel<<<2048, 256, 0, stream>>>(x, Bh, bvec, diag, out);
}

// Round 10
// 721.009 us; speedup vs baseline: 1.9873x; 1.0999x over previous
//
#include <hip/hip_runtime.h>

// ---------------------------------------------------------------------------
// KacLayer: out = x @ (W^T + M) + b, where M = A2 diag(vec) A1 (Kac walks).
// numpy default_rng(4048)/default_rng(4049): PCG64 + SeedSequence (subtractive
// mix) + 32-bit buffered Lemire ints (low u32 half first) — verified r7.
// r10: conflict-free padded groups of 8 built in gen (parallel per-window
// split + wave scan); walk inner loop is branch-free (16 reads, 1 wait,
// 8 rotations, 16 writes per group). No-op pads rotate scratch coord 1024.
// ---------------------------------------------------------------------------

#define NSTEPS 3072
#define NCHUNK 26
#define NRAW (256 * NCHUNK)   // 6656 u64 (need 6144 + rejection slack)
#define NWIN (NSTEPS / 8)     // 384 fixed windows of 8
#define MAXG 2048             // padded-group cap per walk (realistic ~430)

typedef __attribute__((ext_vector_type(8))) short short8;
typedef __attribute__((ext_vector_type(4))) float f32x4;

// ---------------- 128-bit PCG64 (numpy-exact) ------------------------------
struct U128 { unsigned long long lo, hi; };

__device__ __forceinline__ U128 mul128(U128 a, U128 b) {
  U128 r;
  r.lo = a.lo * b.lo;
  r.hi = __umul64hi(a.lo, b.lo) + a.lo * b.hi + a.hi * b.lo;
  return r;
}
__device__ __forceinline__ U128 add128(U128 a, U128 b) {
  U128 r; r.lo = a.lo + b.lo;
  r.hi = a.hi + b.hi + ((r.lo < a.lo) ? 1ull : 0ull);
  return r;
}
__device__ __forceinline__ U128 pcg_mult() {
  return U128{4865540595714422341ull, 2549297995355413924ull};
}
__device__ __forceinline__ U128 pcg_step(U128 st, U128 inc) {
  return add128(mul128(st, pcg_mult()), inc);
}
__device__ __forceinline__ unsigned long long pcg_out(U128 st) {
  unsigned long long x = st.hi ^ st.lo;
  unsigned int rot = (unsigned int)(st.hi >> 58);
  return (x >> rot) | (x << ((64u - rot) & 63u));
}

__device__ void pcg_seed(unsigned int seedval, U128* st, U128* inc) {
  unsigned int pool[4];
  unsigned int hc = 0x43b0d7e5u;                 // INIT_A
  auto hashmix = [&hc](unsigned int v) {
    v ^= hc; hc *= 0x931e8875u; v *= hc; v ^= v >> 16; return v;  // MULT_A
  };
  auto mixf = [](unsigned int x, unsigned int y) {
    unsigned int r = x * 0xca01f9ddu - y * 0x4973f715u;  // SUBTRACT (randutils)
    r ^= r >> 16; return r;
  };
  pool[0] = hashmix(seedval);
  pool[1] = hashmix(0u); pool[2] = hashmix(0u); pool[3] = hashmix(0u);
  for (int s = 0; s < 4; ++s)
    for (int d = 0; d < 4; ++d)
      if (s != d) pool[d] = mixf(pool[d], hashmix(pool[s]));
  unsigned int gc = 0x8b51f9ddu;                 // INIT_B
  unsigned int wv[8];
  for (int k = 0; k < 8; ++k) {
    unsigned int dv = pool[k & 3];
    dv ^= gc; gc *= 0x58f38dedu; dv *= gc; dv ^= dv >> 16;        // MULT_B
    wv[k] = dv;
  }
  unsigned long long o0 = (unsigned long long)wv[0] | ((unsigned long long)wv[1] << 32);
  unsigned long long o1 = (unsigned long long)wv[2] | ((unsigned long long)wv[3] << 32);
  unsigned long long o2 = (unsigned long long)wv[4] | ((unsigned long long)wv[5] << 32);
  unsigned long long o3 = (unsigned long long)wv[6] | ((unsigned long long)wv[7] << 32);
  U128 initstate = { o1, o0 };
  U128 initseq   = { o3, o2 };
  U128 icc; icc.lo = (initseq.lo << 1) | 1ull;
  icc.hi = (initseq.hi << 1) | (initseq.lo >> 63);
  *inc = icc;
  U128 s0 = {0ull, 0ull};
  s0 = pcg_step(s0, icc);
  s0 = add128(s0, initstate);
  s0 = pcg_step(s0, icc);
  *st = s0;
}

__device__ U128 pcg_advance(U128 st, U128 inc, unsigned long long delta) {
  U128 am = {1ull, 0ull}, ap = {0ull, 0ull};
  U128 cm = pcg_mult(), cp = inc;
  while (delta) {
    if (delta & 1ull) {
      am = mul128(am, cm);
      ap = add128(mul128(ap, cm), cp);
    }
    cp = mul128(add128(cm, U128{1ull, 0ull}), cp);
    cm = mul128(cm, cm);
    delta >>= 1;
  }
  return add128(mul128(st, am), ap);
}

__device__ __forceinline__ double first_draw(unsigned int seed) {
  U128 st, inc;
  pcg_seed(seed, &st, &inc);
  st = pcg_step(st, inc);
  return (double)(pcg_out(st) >> 11) * (1.0 / 9007199254740992.0);
}

__device__ __forceinline__ unsigned short f32_to_bf16(float f) {
  unsigned int u = __builtin_bit_cast(unsigned int, f);
  unsigned int r = u + 0x7fffu + ((u >> 16) & 1u);
  return (unsigned short)(r >> 16);
}

// ---------------- Kernel 1: schedule gen + conflict-free padded groups -----
__global__ __launch_bounds__(256) void gen_sched_kernel(uint4* __restrict__ ps0,
                                                        uint4* __restrict__ ps1,
                                                        int* __restrict__ hdr,
                                                        float* __restrict__ diag) {
  __shared__ unsigned long long raw[NRAW];          // 53 KB
  __shared__ unsigned int s_ij[NSTEPS];             // 12 KB
  __shared__ unsigned char s_cm[NSTEPS];            // 3 KB
  __shared__ unsigned short s_wbase[NWIN];          // 768 B
  __shared__ unsigned short s_wcnt[NWIN];
  __shared__ int s_rej, s_p64, s_ng;
  const int w = blockIdx.x;     // walk: seed 4048 + w
  const int t = threadIdx.x;

  if (w == 0 && t == 0) {
    int m1 = first_draw(42u)    != 0.7739560485559633;
    int m2 = first_draw(0u)     != 0.6369616873214543;
    int m3 = first_draw(12345u) != 0.22733602246716966;
    if (m1 + m2 + m3 >= 2)
      diag[0] = 3.0e8f + (float)(m1 + 2 * m2 + 4 * m3) * 3.0e7f;
  }

  U128 st, inc;
  pcg_seed(4048u + (unsigned int)w, &st, &inc);
  U128 mine = pcg_advance(st, inc, (unsigned long long)t * NCHUNK);
  for (int q = 0; q < NCHUNK; ++q) {
    mine = pcg_step(mine, inc);
    raw[t * NCHUNK + q] = pcg_out(mine);
  }
  if (t == 0) s_rej = 0;
  __syncthreads();

  // u32 draw m: LOW half of u64 first, then HIGH (pcg64_next32 buffering)
  auto u32at = [&](int m) -> unsigned int {
    unsigned long long v = raw[m >> 1];
    return (m & 1) ? (unsigned int)(v >> 32) : (unsigned int)v;
  };

  for (int k = t; k < NSTEPS; k += 256) {
    unsigned long long m = (unsigned long long)u32at(NSTEPS + k) * 1023ull;
    if ((unsigned int)m < 4u) atomicAdd(&s_rej, 1);
  }
  __syncthreads();

  if (s_rej == 0) {
    for (int k = t; k < NSTEPS; k += 256) {
      unsigned int iv = u32at(k) >> 22;                 // (u32*1024)>>32
      unsigned long long m = (unsigned long long)u32at(NSTEPS + k) * 1023ull;
      unsigned int off = 1u + (unsigned int)(m >> 32);
      unsigned int jv = (iv + off) & 1023u;
      s_ij[k] = (iv << 16) | jv;
    }
    if (t == 0) s_p64 = NSTEPS;        // 6144 u32 consumed -> u64 idx 3072
  } else if (t == 0) {
    // exact sequential replay with rejections (P ~ 3e-6 per walk)
    int p = 0;
    for (int k = 0; k < NSTEPS; ++k) s_ij[k] = (u32at(p++) >> 22) << 16;
    for (int k = 0; k < NSTEPS; ++k) {
      unsigned long long m = (unsigned long long)u32at(p++) * 1023ull;
      unsigned int lo = (unsigned int)m;
      if (lo < 1023u) {
        while (lo < 4u) { m = (unsigned long long)u32at(p++) * 1023ull; lo = (unsigned int)m; }
      }
      unsigned int off = 1u + (unsigned int)(m >> 32);
      unsigned int iv = s_ij[k] >> 16;
      s_ij[k] = (iv << 16) | ((iv + off) & 1023u);
    }
    s_p64 = (p + 1) >> 1;
  }
  __syncthreads();

  // conflict masks: bit b (1..7) set iff step k shares a coord with step k-b
  for (int k = t; k < NSTEPS; k += 256) {
    unsigned int a = s_ij[k];
    unsigned int ia = a >> 16, ja = a & 0xffffu;
    unsigned int cm = 0;
    #pragma unroll
    for (int b = 1; b <= 7; ++b) {
      if (k - b >= 0) {
        unsigned int e = s_ij[k - b];
        unsigned int ie = e >> 16, je = e & 0xffffu;
        if (ia == ie || ia == je || ja == ie || ja == je) cm |= (1u << b);
      }
    }
    s_cm[k] = (unsigned char)cm;
  }
  __syncthreads();

  // per-window (8 steps) subgroup counts
  for (int wi = t; wi < NWIN; wi += 256) {
    int cs = 0, cnt = 1;
    #pragma unroll
    for (int o = 1; o < 8; ++o) {
      unsigned int mask = (1u << (o - cs + 1)) - 2u;   // bits 1..(o-cs)
      if (s_cm[8 * wi + o] & mask) { ++cnt; cs = o; }
    }
    s_wcnt[wi] = (unsigned short)cnt;
  }
  __syncthreads();

  // exclusive bases via one-wave shfl scan (6 windows per lane)
  if (t < 64) {
    int cnts[6]; int tot = 0;
    #pragma unroll
    for (int q = 0; q < 6; ++q) {
      int widx = t * 6 + q;
      cnts[q] = (widx < NWIN) ? (int)s_wcnt[widx] : 0;
      tot += cnts[q];
    }
    int sc = tot;
    for (int off = 1; off < 64; off <<= 1) {
      int v = __shfl_up(sc, off);
      if (t >= off) sc += v;
    }
    int base = sc - tot;
    #pragma unroll
    for (int q = 0; q < 6; ++q) {
      int widx = t * 6 + q;
      if (widx < NWIN) { s_wbase[widx] = (unsigned short)base; base += cnts[q]; }
    }
    if (t == 63) s_ng = sc;
  }
  __syncthreads();

  const int ng = s_ng;
  if (t == 0) {
    hdr[w] = (ng <= MAXG) ? ng : MAXG;
    if (ng > MAXG) diag[3] = 6.0e8f;
  }

  // emission: padded groups of 8; pads rotate scratch coord 1024 by identity
  uint4* ps = w ? ps1 : ps0;
  const int base64 = s_p64;
  const uint4 noop = { (1024u << 16) | 1024u, __float_as_uint(1.0f),
                       __float_as_uint(0.0f), 0u };
  for (int wi = t; wi < NWIN; wi += 256) {
    int g = s_wbase[wi];
    int cs = 0;
    for (int o = 0; o < 8; ++o) {
      if (o > 0) {
        unsigned int mask = (1u << (o - cs + 1)) - 2u;
        if (s_cm[8 * wi + o] & mask) {
          for (int p = o - cs; p < 8; ++p)
            if (g < MAXG) ps[g * 8 + p] = noop;
          ++g; cs = o;
        }
      }
      int k = 8 * wi + o;
      unsigned long long v = raw[base64 + k];
      double d = (double)(v >> 11) * (1.0 / 9007199254740992.0);
      double ang = d * 6.283185307179586;
      uint4 ent;
      ent.x = s_ij[k];
      ent.y = __float_as_uint((float)cos(ang));
      ent.z = __float_as_uint((float)sin(ang));
      ent.w = 0u;
      if (g < MAXG) ps[g * 8 + (o - cs)] = ent;
    }
    for (int p = 8 - cs; p < 8; ++p)
      if (g < MAXG) ps[g * 8 + p] = noop;
  }
}

// ---------------- Kernel 2: grouped conflict-free Kac walk -----------------
// L[1025 coords][16 rows] (coord 1024 = no-op scratch). Lane r owns row r.
// Per group: prefetch next 8 sched entries (global), 16 independent LDS
// reads, one wait, 8 rotations, 16 writes — branch-free, exact.
__device__ void walk_groups(const uint4* __restrict__ sp, int ng,
                            float* __restrict__ L, int r) {
  uint4 cur[8], nxt[8];
  #pragma unroll
  for (int q = 0; q < 8; ++q) cur[q] = sp[q];
  for (int g = 0; g < ng; ++g) {
    const int gn = (g + 1 < ng) ? g + 1 : g;
    #pragma unroll
    for (int q = 0; q < 8; ++q) nxt[q] = sp[gn * 8 + q];
    float xi[8], xj[8];
    #pragma unroll
    for (int q = 0; q < 8; ++q) {
      int i = (int)(cur[q].x >> 16), j = (int)(cur[q].x & 0xffffu);
      xi[q] = L[i * 16 + r];
      xj[q] = L[j * 16 + r];
    }
    #pragma unroll
    for (int q = 0; q < 8; ++q) {
      int i = (int)(cur[q].x >> 16), j = (int)(cur[q].x & 0xffffu);
      float c = __uint_as_float(cur[q].y);
      float s = __uint_as_float(cur[q].z);
      L[i * 16 + r] = fmaf(c, xi[q], -s * xj[q]);
      L[j * 16 + r] = fmaf(s, xi[q],  c * xj[q]);
    }
    #pragma unroll
    for (int q = 0; q < 8; ++q) cur[q] = nxt[q];
  }
}

__global__ __launch_bounds__(256) void walk_kernel(const uint4* __restrict__ ps0,
                                                   const uint4* __restrict__ ps1,
                                                   const int* __restrict__ hdr,
                                                   const float* __restrict__ W,
                                                   const float* __restrict__ vec,
                                                   unsigned short* __restrict__ Bh,
                                                   float* __restrict__ diag) {
  __shared__ float L[1025 * 16];        // 65.6 KB
  const int b = blockIdx.x;             // 0..63
  const int t = threadIdx.x;
  const int d0 = b * 16;
  const int ng0 = hdr[0], ng1 = hdr[1];
  for (int idx = t; idx < 1025 * 16; idx += 256) {
    int c = idx >> 4, r = idx & 15;
    L[idx] = (c == d0 + r) ? 1.0f : 0.0f;
  }
  __syncthreads();
  if (t < 16) walk_groups(ps0, ng0, L, t);
  __syncthreads();
  {  // Givens chains preserve unit norms
    bool bad = false;
    if (b == 0 && t < 16) {
      float ss = 0.0f;
      for (int c = 0; c < 1024; ++c) { float v = L[c * 16 + t]; ss += v * v; }
      bad = fabsf(ss - 1.0f) > 2.0e-3f;
    }
    unsigned long long bm = __ballot(bad);
    if (b == 0 && t == 0 && bm) diag[1] = 2.0e7f;
  }
  __syncthreads();
  for (int idx = t; idx < 1024 * 16; idx += 256) L[idx] *= vec[idx >> 4];
  __syncthreads();
  if (t < 16) walk_groups(ps1, ng1, L, t);
  __syncthreads();
  // B[e][d0+dl] = W[e][d0+dl] + M[e][d0+dl];  M[e][d0+dl] = L[e*16+dl]
  const int dl = t & 15;
  const int eb = t >> 4;
  for (int p = 0; p < 64; ++p) {
    int e = eb + p * 16;
    Bh[e * 1024 + d0 + dl] = f32_to_bf16(W[e * 1024 + d0 + dl] + L[e * 16 + dl]);
  }
}

// ---------------- Kernel 3: bf16 GEMM out = x @ B^T + b --------------------
__device__ __forceinline__ int swz(int row, int colbyte) {
  return row * 128 + (colbyte ^ ((row & 7) << 4));
}

__global__ __launch_bounds__(256) void gemm_kernel(const float* __restrict__ x,
                                                   const unsigned short* __restrict__ Bhg,
                                                   const float* __restrict__ bvec,
                                                   const float* __restrict__ diag,
                                                   float* __restrict__ out) {
  __shared__ unsigned short Ash[128 * 64];   // 16 KB, swizzled
  __shared__ unsigned short Bsh[128 * 64];
  const int t = threadIdx.x;
  const int bm = blockIdx.x & 255;           // panel-major for XCD L2 locality
  const int bn = blockIdx.x >> 8;
  const int m0 = bm * 128, n0 = bn * 128;
  const int l = t & 63, w = t >> 6;
  const int wr = w >> 1, wc = w & 1;
  const int lr = l & 15, lk = l >> 4;
  const int arb = t >> 4, akb = (t & 15) << 3;
  const int brb = t >> 3, bkb = (t & 7) << 4;

  f32x4 acc[4][4] = {};
  float4 ra[8];
  uint4 rb[4];

  #pragma unroll
  for (int p = 0; p < 8; ++p)
    ra[p] = *(const float4*)&x[(size_t)(m0 + arb + p * 16) * 1024 + (akb >> 1)];
  #pragma unroll
  for (int p = 0; p < 4; ++p)
    rb[p] = *(const uint4*)&Bhg[(size_t)(n0 + brb + p * 32) * 1024 + (bkb >> 1)];

  for (int kt = 0; kt < 16; ++kt) {
    #pragma unroll
    for (int p = 0; p < 8; ++p) {
      ushort4 hv;
      hv.x = f32_to_bf16(ra[p].x); hv.y = f32_to_bf16(ra[p].y);
      hv.z = f32_to_bf16(ra[p].z); hv.w = f32_to_bf16(ra[p].w);
      *(ushort4*)((char*)Ash + swz(arb + p * 16, akb)) = hv;
    }
    #pragma unroll
    for (int p = 0; p < 4; ++p)
      *(uint4*)((char*)Bsh + swz(brb + p * 32, bkb)) = rb[p];
    __syncthreads();

    if (kt + 1 < 16) {
      const int k0 = (kt + 1) * 64;
      #pragma unroll
      for (int p = 0; p < 8; ++p)
        ra[p] = *(const float4*)&x[(size_t)(m0 + arb + p * 16) * 1024 + k0 + (akb >> 1)];
      #pragma unroll
      for (int p = 0; p < 4; ++p)
        rb[p] = *(const uint4*)&Bhg[(size_t)(n0 + brb + p * 32) * 1024 + k0 + (bkb >> 1)];
    }

    #pragma unroll
    for (int kk = 0; kk < 64; kk += 32) {
      short8 af[4], bf[4];
      const int cb = kk * 2 + lk * 16;
      #pragma unroll
      for (int m4 = 0; m4 < 4; ++m4)
        af[m4] = *(const short8*)((const char*)Ash + swz(wr * 64 + m4 * 16 + lr, cb));
      #pragma unroll
      for (int n4 = 0; n4 < 4; ++n4)
        bf[n4] = *(const short8*)((const char*)Bsh + swz(wc * 64 + n4 * 16 + lr, cb));
      #pragma unroll
      for (int m4 = 0; m4 < 4; ++m4)
        #pragma unroll
        for (int n4 = 0; n4 < 4; ++n4)
          acc[m4][n4] = __builtin_amdgcn_mfma_f32_16x16x32_bf16(af[m4], bf[n4], acc[m4][n4], 0, 0, 0);
    }
    __syncthreads();
  }

  #pragma unroll
  for (int n4 = 0; n4 < 4; ++n4) {
    const int col = n0 + wc * 64 + n4 * 16 + lr;
    const float bias = bvec[col];
    #pragma unroll
    for (int m4 = 0; m4 < 4; ++m4) {
      const int row = m0 + wr * 64 + m4 * 16 + lk * 4;
      #pragma unroll
      for (int q = 0; q < 4; ++q)
        out[(size_t)(row + q) * 1024 + col] = acc[m4][n4][q] + bias;
    }
  }

  if (blockIdx.x == 0 && t == 0) {
    float dg = diag[0] + diag[1] + diag[3];
    if (dg != 0.0f) out[0] += dg;
  }
}

__global__ void signal_kernel(float* out, float val) { out[0] = val; }

// ---------------------------------------------------------------------------
extern "C" void kernel_launch(void* const* d_in, const int* in_sizes, int n_in,
                              void* d_out, int out_size, void* d_ws, size_t ws_size,
                              hipStream_t stream) {
  const float* x    = (const float*)d_in[0];
  const float* W    = (const float*)d_in[1];
  const float* bvec = (const float*)d_in[2];
  const float* vec  = (const float*)d_in[3];
  float* out = (float*)d_out;

  const size_t MB = 1024 * 1024;
  // layout: diag @0 (64B), hdr @256, ps0 @8192 (256KB), ps1 @270336 (256KB),
  //         Bh @1MB (2MB)
  const size_t need = 3 * MB;
  if (ws_size < need) {
    signal_kernel<<<1, 1, 0, stream>>>(out, 4.0e8f + (float)(ws_size >> 20) * 1000.0f);
    return;
  }
  float* diag = (float*)d_ws;
  int* hdr = (int*)((char*)d_ws + 256);
  uint4* ps0 = (uint4*)((char*)d_ws + 8192);
  uint4* ps1 = (uint4*)((char*)d_ws + 8192 + MAXG * 8 * 16);
  unsigned short* Bh = (unsigned short*)((char*)d_ws + MB);

  hipMemsetAsync(diag, 0, 64, stream);
  gen_sched_kernel<<<2, 256, 0, stream>>>(ps0, ps1, hdr, diag);
  walk_kernel<<<64, 256, 0, stream>>>(ps0, ps1, hdr, W, vec, Bh, diag);
  gemm_kernel<<<2048, 256, 0, stream>>>(x, Bh, bvec, diag, out);
}

// Round 11
// 430.825 us; speedup vs baseline: 3.3258x; 1.6736x over previous
//
#include <hip/hip_runtime.h>

// ---------------------------------------------------------------------------
// KacLayer: out = x @ (W^T + M) + b, where M = A2 diag(vec) A1 (Kac walks).
// numpy default_rng(4048)/default_rng(4049): PCG64 + SeedSequence (subtractive
// mix) + 32-bit buffered Lemire ints (low u32 half first) — verified r7.
// r11: LEVEL-SCHEDULED walk. Gen computes the dependency-DAG level of each
// rotation (parallel bucket preds + monotone relaxation), emits level-ordered
// groups of 16 mutually-disjoint rotations (pads rotate scratch coord 1024).
// Walk: 64 lanes = 16 cols x 4 subs, 4 rotations/lane/group, schedule in LDS,
// stride-17 state layout. Disjointness within groups => bit-exact commuting.
// ---------------------------------------------------------------------------

#define NSTEPS 3072
#define NCHUNK 26
#define NRAW (256 * NCHUNK)   // 6656 u64 (need 6144 + rejection slack)
#define MAXS 4608             // schedule slots per phase (3072 + pads)
#define MAXLEV 256

typedef __attribute__((ext_vector_type(8))) short short8;
typedef __attribute__((ext_vector_type(4))) float f32x4;

// ---------------- 128-bit PCG64 (numpy-exact) ------------------------------
struct U128 { unsigned long long lo, hi; };

__device__ __forceinline__ U128 mul128(U128 a, U128 b) {
  U128 r;
  r.lo = a.lo * b.lo;
  r.hi = __umul64hi(a.lo, b.lo) + a.lo * b.hi + a.hi * b.lo;
  return r;
}
__device__ __forceinline__ U128 add128(U128 a, U128 b) {
  U128 r; r.lo = a.lo + b.lo;
  r.hi = a.hi + b.hi + ((r.lo < a.lo) ? 1ull : 0ull);
  return r;
}
__device__ __forceinline__ U128 pcg_mult() {
  return U128{4865540595714422341ull, 2549297995355413924ull};
}
__device__ __forceinline__ U128 pcg_step(U128 st, U128 inc) {
  return add128(mul128(st, pcg_mult()), inc);
}
__device__ __forceinline__ unsigned long long pcg_out(U128 st) {
  unsigned long long x = st.hi ^ st.lo;
  unsigned int rot = (unsigned int)(st.hi >> 58);
  return (x >> rot) | (x << ((64u - rot) & 63u));
}

__device__ void pcg_seed(unsigned int seedval, U128* st, U128* inc) {
  unsigned int pool[4];
  unsigned int hc = 0x43b0d7e5u;                 // INIT_A
  auto hashmix = [&hc](unsigned int v) {
    v ^= hc; hc *= 0x931e8875u; v *= hc; v ^= v >> 16; return v;  // MULT_A
  };
  auto mixf = [](unsigned int x, unsigned int y) {
    unsigned int r = x * 0xca01f9ddu - y * 0x4973f715u;  // SUBTRACT (randutils)
    r ^= r >> 16; return r;
  };
  pool[0] = hashmix(seedval);
  pool[1] = hashmix(0u); pool[2] = hashmix(0u); pool[3] = hashmix(0u);
  for (int s = 0; s < 4; ++s)
    for (int d = 0; d < 4; ++d)
      if (s != d) pool[d] = mixf(pool[d], hashmix(pool[s]));
  unsigned int gc = 0x8b51f9ddu;                 // INIT_B
  unsigned int wv[8];
  for (int k = 0; k < 8; ++k) {
    unsigned int dv = pool[k & 3];
    dv ^= gc; gc *= 0x58f38dedu; dv *= gc; dv ^= dv >> 16;        // MULT_B
    wv[k] = dv;
  }
  unsigned long long o0 = (unsigned long long)wv[0] | ((unsigned long long)wv[1] << 32);
  unsigned long long o1 = (unsigned long long)wv[2] | ((unsigned long long)wv[3] << 32);
  unsigned long long o2 = (unsigned long long)wv[4] | ((unsigned long long)wv[5] << 32);
  unsigned long long o3 = (unsigned long long)wv[6] | ((unsigned long long)wv[7] << 32);
  U128 initstate = { o1, o0 };
  U128 initseq   = { o3, o2 };
  U128 icc; icc.lo = (initseq.lo << 1) | 1ull;
  icc.hi = (initseq.hi << 1) | (initseq.lo >> 63);
  *inc = icc;
  U128 s0 = {0ull, 0ull};
  s0 = pcg_step(s0, icc);
  s0 = add128(s0, initstate);
  s0 = pcg_step(s0, icc);
  *st = s0;
}

__device__ U128 pcg_advance(U128 st, U128 inc, unsigned long long delta) {
  U128 am = {1ull, 0ull}, ap = {0ull, 0ull};
  U128 cm = pcg_mult(), cp = inc;
  while (delta) {
    if (delta & 1ull) {
      am = mul128(am, cm);
      ap = add128(mul128(ap, cm), cp);
    }
    cp = mul128(add128(cm, U128{1ull, 0ull}), cp);
    cm = mul128(cm, cm);
    delta >>= 1;
  }
  return add128(mul128(st, am), ap);
}

__device__ __forceinline__ double first_draw(unsigned int seed) {
  U128 st, inc;
  pcg_seed(seed, &st, &inc);
  st = pcg_step(st, inc);
  return (double)(pcg_out(st) >> 11) * (1.0 / 9007199254740992.0);
}

__device__ __forceinline__ unsigned short f32_to_bf16(float f) {
  unsigned int u = __builtin_bit_cast(unsigned int, f);
  unsigned int r = u + 0x7fffu + ((u >> 16) & 1u);
  return (unsigned short)(r >> 16);
}

// ---------------- Kernel 1: schedule gen + level scheduling ----------------
__global__ __launch_bounds__(256) void gen_sched_kernel(uint4* __restrict__ ps0,
                                                        uint4* __restrict__ ps1,
                                                        int* __restrict__ hdr,
                                                        float* __restrict__ diag) {
  __shared__ unsigned long long raw[NRAW];          // 53 KB
  __shared__ unsigned int s_ij[NSTEPS];             // 12 KB
  __shared__ unsigned short s_list[2 * NSTEPS];     // 12 KB  (k<<1 | side)
  __shared__ short s_predA[NSTEPS];                 // 6 KB
  __shared__ short s_predB[NSTEPS];                 // 6 KB
  __shared__ unsigned short s_lev[NSTEPS];          // 6 KB
  __shared__ int s_cnt[1024];                       // 4 KB (also cursors)
  __shared__ int s_base[1025];                      // 4 KB
  __shared__ int s_lcnt[MAXLEV];                    // 1 KB (also cursors)
  __shared__ int s_lbase[MAXLEV];                   // 1 KB
  __shared__ int s_rej, s_p64, s_changed, s_maxlev, s_ns;
  const int w = blockIdx.x;     // walk: seed 4048 + w
  const int t = threadIdx.x;

  if (w == 0 && t == 0) {
    int m1 = first_draw(42u)    != 0.7739560485559633;
    int m2 = first_draw(0u)     != 0.6369616873214543;
    int m3 = first_draw(12345u) != 0.22733602246716966;
    if (m1 + m2 + m3 >= 2)
      diag[0] = 3.0e8f + (float)(m1 + 2 * m2 + 4 * m3) * 3.0e7f;
  }

  U128 st, inc;
  pcg_seed(4048u + (unsigned int)w, &st, &inc);
  U128 mine = pcg_advance(st, inc, (unsigned long long)t * NCHUNK);
  for (int q = 0; q < NCHUNK; ++q) {
    mine = pcg_step(mine, inc);
    raw[t * NCHUNK + q] = pcg_out(mine);
  }
  if (t == 0) { s_rej = 0; s_maxlev = 1; }
  __syncthreads();

  // u32 draw m: LOW half of u64 first, then HIGH (pcg64_next32 buffering)
  auto u32at = [&](int m) -> unsigned int {
    unsigned long long v = raw[m >> 1];
    return (m & 1) ? (unsigned int)(v >> 32) : (unsigned int)v;
  };

  for (int k = t; k < NSTEPS; k += 256) {
    unsigned long long m = (unsigned long long)u32at(NSTEPS + k) * 1023ull;
    if ((unsigned int)m < 4u) atomicAdd(&s_rej, 1);
  }
  __syncthreads();

  if (s_rej == 0) {
    for (int k = t; k < NSTEPS; k += 256) {
      unsigned int iv = u32at(k) >> 22;                 // (u32*1024)>>32
      unsigned long long m = (unsigned long long)u32at(NSTEPS + k) * 1023ull;
      unsigned int off = 1u + (unsigned int)(m >> 32);
      unsigned int jv = (iv + off) & 1023u;
      s_ij[k] = (iv << 16) | jv;
    }
    if (t == 0) s_p64 = NSTEPS;        // 6144 u32 consumed -> u64 idx 3072
  } else if (t == 0) {
    // exact sequential replay with rejections (P ~ 3e-6 per walk)
    int p = 0;
    for (int k = 0; k < NSTEPS; ++k) s_ij[k] = (u32at(p++) >> 22) << 16;
    for (int k = 0; k < NSTEPS; ++k) {
      unsigned long long m = (unsigned long long)u32at(p++) * 1023ull;
      unsigned int lo = (unsigned int)m;
      if (lo < 1023u) {
        while (lo < 4u) { m = (unsigned long long)u32at(p++) * 1023ull; lo = (unsigned int)m; }
      }
      unsigned int off = 1u + (unsigned int)(m >> 32);
      unsigned int iv = s_ij[k] >> 16;
      s_ij[k] = (iv << 16) | ((iv + off) & 1023u);
    }
    s_p64 = (p + 1) >> 1;
  }
  __syncthreads();

  // --- per-coord touch counts -> bases ---------------------------------
  for (int c = t; c < 1024; c += 256) s_cnt[c] = 0;
  __syncthreads();
  for (int k = t; k < NSTEPS; k += 256) {
    atomicAdd(&s_cnt[s_ij[k] >> 16], 1);
    atomicAdd(&s_cnt[s_ij[k] & 0xffffu], 1);
  }
  __syncthreads();
  if (t < 64) {
    int loc[16], tot = 0;
    #pragma unroll
    for (int q = 0; q < 16; ++q) { loc[q] = s_cnt[t * 16 + q]; tot += loc[q]; }
    int sc = tot;
    for (int off = 1; off < 64; off <<= 1) {
      int v = __shfl_up(sc, off);
      if (t >= off) sc += v;
    }
    int base = sc - tot;
    #pragma unroll
    for (int q = 0; q < 16; ++q) { s_base[t * 16 + q] = base; base += loc[q]; }
  }
  if (t == 0) s_base[1024] = 2 * NSTEPS;
  __syncthreads();

  // --- scatter (k,side) into buckets, sort, derive preds ----------------
  for (int c = t; c < 1024; c += 256) s_cnt[c] = 0;
  __syncthreads();
  for (int k = t; k < NSTEPS; k += 256) {
    unsigned int iv = s_ij[k] >> 16, jv = s_ij[k] & 0xffffu;
    int p1 = atomicAdd(&s_cnt[iv], 1);
    s_list[s_base[iv] + p1] = (unsigned short)(k << 1);
    int p2 = atomicAdd(&s_cnt[jv], 1);
    s_list[s_base[jv] + p2] = (unsigned short)((k << 1) | 1);
  }
  __syncthreads();
  for (int c = t; c < 1024; c += 256) {
    int b0 = s_base[c], b1 = s_base[c + 1];
    for (int a = b0 + 1; a < b1; ++a) {       // insertion sort (~6 elems)
      unsigned short v = s_list[a];
      int p = a;
      while (p > b0 && s_list[p - 1] > v) { s_list[p] = s_list[p - 1]; --p; }
      s_list[p] = v;
    }
    short prev = -1;
    for (int a = b0; a < b1; ++a) {
      int e = s_list[a]; int k = e >> 1;
      if (e & 1) s_predB[k] = prev; else s_predA[k] = prev;
      prev = (short)k;
    }
  }
  __syncthreads();

  // --- monotone relaxation to longest-path levels -----------------------
  for (int k = t; k < NSTEPS; k += 256) s_lev[k] = 1;
  __syncthreads();
  for (int it = 0; it < 300; ++it) {
    if (t == 0) s_changed = 0;
    __syncthreads();
    for (int k = t; k < NSTEPS; k += 256) {
      int la = s_predA[k] >= 0 ? (int)s_lev[s_predA[k]] : 0;
      int lb = s_predB[k] >= 0 ? (int)s_lev[s_predB[k]] : 0;
      int nl = 1 + (la > lb ? la : lb);
      if (nl > (int)s_lev[k]) {
        if (nl >= MAXLEV) { nl = MAXLEV - 1; diag[3] = 7.0e8f; }
        s_lev[k] = (unsigned short)nl; s_changed = 1;
      }
    }
    __syncthreads();
    int done = !s_changed;
    __syncthreads();
    if (done) break;
  }

  // --- histogram levels, padded bases (groups of 16) --------------------
  for (int L = t; L < MAXLEV; L += 256) s_lcnt[L] = 0;
  __syncthreads();
  for (int k = t; k < NSTEPS; k += 256) {
    atomicAdd(&s_lcnt[s_lev[k]], 1);
    atomicMax(&s_maxlev, (int)s_lev[k]);
  }
  __syncthreads();
  if (t == 0) {
    int run = 0;
    for (int L = 1; L <= s_maxlev; ++L) {
      s_lbase[L] = run;
      run += (s_lcnt[L] + 15) & ~15;
    }
    s_ns = run;
    hdr[w] = (run <= MAXS) ? run : MAXS;
    if (run > MAXS) diag[3] = 6.0e8f;
  }
  __syncthreads();
  const int ns = (s_ns <= MAXS) ? s_ns : MAXS;
  uint4* ps = w ? ps1 : ps0;
  uint4 noop;
  noop.x = (17408u << 16) | 17408u;   // scratch coord 1024 (*17)
  noop.y = __float_as_uint(1.0f);
  noop.z = __float_as_uint(0.0f);
  noop.w = 0u;
  for (int s = t; s < ns; s += 256) ps[s] = noop;
  for (int L = t; L < MAXLEV; L += 256) s_lcnt[L] = 0;   // reuse as cursors
  __syncthreads();
  const int base64 = s_p64;
  for (int k = t; k < NSTEPS; k += 256) {
    int lv = s_lev[k];
    int pos = atomicAdd(&s_lcnt[lv], 1);
    int slot = s_lbase[lv] + pos;
    if (slot < MAXS) {
      unsigned long long v = raw[base64 + k];
      double d = (double)(v >> 11) * (1.0 / 9007199254740992.0);
      double ang = d * 6.283185307179586;
      unsigned int ij = s_ij[k];
      unsigned int i17 = (ij >> 16) * 17u, j17 = (ij & 0xffffu) * 17u;
      uint4 ent;
      ent.x = (i17 << 16) | j17;
      ent.y = __float_as_uint((float)cos(ang));
      ent.z = __float_as_uint((float)sin(ang));
      ent.w = 0u;
      ps[slot] = ent;
    }
  }
}

// ---------------- Kernel 2: level-grouped Kac walk + combine ---------------
// L[c*17 + col]: 1025 coords (1024 = pad scratch), stride 17 breaks bank
// aliasing across the 4 sub-lanes. 64 lanes = 16 cols x 4 subs; each lane
// applies rotations {sub, sub+4, sub+8, sub+12} of each 16-disjoint group to
// its column. Cross-group ordering: same-wave in-order LDS.
__device__ void walk_groups(const uint4* __restrict__ SG, int ng,
                            float* __restrict__ L, int col, int sub) {
  if (ng <= 0) return;
  uint4 c0 = SG[sub], c1 = SG[sub + 4], c2 = SG[sub + 8], c3 = SG[sub + 12];
  for (int g = 0; g < ng; ++g) {
    const int nb = ((g + 1 < ng) ? (g + 1) : g) << 4;
    uint4 n0 = SG[nb + sub], n1 = SG[nb + sub + 4];
    uint4 n2 = SG[nb + sub + 8], n3 = SG[nb + sub + 12];
    const int i0 = (int)(c0.x >> 16) + col, j0 = (int)(c0.x & 0xffffu) + col;
    const int i1 = (int)(c1.x >> 16) + col, j1 = (int)(c1.x & 0xffffu) + col;
    const int i2 = (int)(c2.x >> 16) + col, j2 = (int)(c2.x & 0xffffu) + col;
    const int i3 = (int)(c3.x >> 16) + col, j3 = (int)(c3.x & 0xffffu) + col;
    float a0 = L[i0], b0 = L[j0], a1 = L[i1], b1 = L[j1];
    float a2 = L[i2], b2 = L[j2], a3 = L[i3], b3 = L[j3];
    const float p0 = __uint_as_float(c0.y), q0 = __uint_as_float(c0.z);
    const float p1 = __uint_as_float(c1.y), q1 = __uint_as_float(c1.z);
    const float p2 = __uint_as_float(c2.y), q2 = __uint_as_float(c2.z);
    const float p3 = __uint_as_float(c3.y), q3 = __uint_as_float(c3.z);
    L[i0] = fmaf(p0, a0, -q0 * b0); L[j0] = fmaf(q0, a0, p0 * b0);
    L[i1] = fmaf(p1, a1, -q1 * b1); L[j1] = fmaf(q1, a1, p1 * b1);
    L[i2] = fmaf(p2, a2, -q2 * b2); L[j2] = fmaf(q2, a2, p2 * b2);
    L[i3] = fmaf(p3, a3, -q3 * b3); L[j3] = fmaf(q3, a3, p3 * b3);
    c0 = n0; c1 = n1; c2 = n2; c3 = n3;
  }
}

__global__ __launch_bounds__(256) void walk_kernel(const uint4* __restrict__ ps0,
                                                   const uint4* __restrict__ ps1,
                                                   const int* __restrict__ hdr,
                                                   const float* __restrict__ W,
                                                   const float* __restrict__ vec,
                                                   unsigned short* __restrict__ Bh,
                                                   float* __restrict__ diag) {
  __shared__ float L[1025 * 17];     // 69.7 KB
  __shared__ uint4 SG[MAXS];         // 72 KB
  const int b = blockIdx.x;          // 0..63
  const int t = threadIdx.x;
  const int d0 = b * 16;
  int ns0 = hdr[0]; if (ns0 > MAXS) ns0 = MAXS;
  int ns1 = hdr[1]; if (ns1 > MAXS) ns1 = MAXS;

  for (int idx = t; idx < 1025 * 16; idx += 256) {
    int c = idx >> 4, col = idx & 15;
    L[c * 17 + col] = (c == d0 + col) ? 1.0f : 0.0f;
  }
  for (int s = t; s < ns0; s += 256) SG[s] = ps0[s];
  __syncthreads();
  if (t < 64) walk_groups(SG, ns0 >> 4, L, t & 15, t >> 4);
  __syncthreads();
  {  // Givens chains preserve unit norms
    bool bad = false;
    if (b == 0 && t < 16) {
      float ss = 0.0f;
      for (int c = 0; c < 1024; ++c) { float v = L[c * 17 + t]; ss += v * v; }
      bad = fabsf(ss - 1.0f) > 2.0e-3f;
    }
    unsigned long long bm = __ballot(bad);
    if (b == 0 && t == 0 && bm) diag[1] = 2.0e7f;
  }
  __syncthreads();
  for (int idx = t; idx < 1024 * 16; idx += 256) {
    int c = idx >> 4, col = idx & 15;
    L[c * 17 + col] *= vec[c];
  }
  for (int s = t; s < ns1; s += 256) SG[s] = ps1[s];
  __syncthreads();
  if (t < 64) walk_groups(SG, ns1 >> 4, L, t & 15, t >> 4);
  __syncthreads();
  // B[e][d0+dl] = W[e][d0+dl] + M[e][d0+dl];  M[e][d0+dl] = L[e*17+dl]
  const int dl = t & 15;
  const int eb = t >> 4;
  for (int p = 0; p < 64; ++p) {
    int e = eb + p * 16;
    Bh[e * 1024 + d0 + dl] = f32_to_bf16(W[e * 1024 + d0 + dl] + L[e * 17 + dl]);
  }
}

// ---------------- Kernel 3: bf16 GEMM out = x @ B^T + b --------------------
__device__ __forceinline__ int swz(int row, int colbyte) {
  return row * 128 + (colbyte ^ ((row & 7) << 4));
}

__global__ __launch_bounds__(256) void gemm_kernel(const float* __restrict__ x,
                                                   const unsigned short* __restrict__ Bhg,
                                                   const float* __restrict__ bvec,
                                                   const float* __restrict__ diag,
                                                   float* __restrict__ out) {
  __shared__ unsigned short Ash[128 * 64];   // 16 KB, swizzled
  __shared__ unsigned short Bsh[128 * 64];
  const int t = threadIdx.x;
  const int bm = blockIdx.x & 255;           // panel-major for XCD L2 locality
  const int bn = blockIdx.x >> 8;
  const int m0 = bm * 128, n0 = bn * 128;
  const int l = t & 63, w = t >> 6;
  const int wr = w >> 1, wc = w & 1;
  const int lr = l & 15, lk = l >> 4;
  const int arb = t >> 4, akb = (t & 15) << 3;
  const int brb = t >> 3, bkb = (t & 7) << 4;

  f32x4 acc[4][4] = {};
  float4 ra[8];
  uint4 rb[4];

  #pragma unroll
  for (int p = 0; p < 8; ++p)
    ra[p] = *(const float4*)&x[(size_t)(m0 + arb + p * 16) * 1024 + (akb >> 1)];
  #pragma unroll
  for (int p = 0; p < 4; ++p)
    rb[p] = *(const uint4*)&Bhg[(size_t)(n0 + brb + p * 32) * 1024 + (bkb >> 1)];

  for (int kt = 0; kt < 16; ++kt) {
    #pragma unroll
    for (int p = 0; p < 8; ++p) {
      ushort4 hv;
      hv.x = f32_to_bf16(ra[p].x); hv.y = f32_to_bf16(ra[p].y);
      hv.z = f32_to_bf16(ra[p].z); hv.w = f32_to_bf16(ra[p].w);
      *(ushort4*)((char*)Ash + swz(arb + p * 16, akb)) = hv;
    }
    #pragma unroll
    for (int p = 0; p < 4; ++p)
      *(uint4*)((char*)Bsh + swz(brb + p * 32, bkb)) = rb[p];
    __syncthreads();

    if (kt + 1 < 16) {
      const int k0 = (kt + 1) * 64;
      #pragma unroll
      for (int p = 0; p < 8; ++p)
        ra[p] = *(const float4*)&x[(size_t)(m0 + arb + p * 16) * 1024 + k0 + (akb >> 1)];
      #pragma unroll
      for (int p = 0; p < 4; ++p)
        rb[p] = *(const uint4*)&Bhg[(size_t)(n0 + brb + p * 32) * 1024 + k0 + (bkb >> 1)];
    }

    #pragma unroll
    for (int kk = 0; kk < 64; kk += 32) {
      short8 af[4], bf[4];
      const int cb = kk * 2 + lk * 16;
      #pragma unroll
      for (int m4 = 0; m4 < 4; ++m4)
        af[m4] = *(const short8*)((const char*)Ash + swz(wr * 64 + m4 * 16 + lr, cb));
      #pragma unroll
      for (int n4 = 0; n4 < 4; ++n4)
        bf[n4] = *(const short8*)((const char*)Bsh + swz(wc * 64 + n4 * 16 + lr, cb));
      #pragma unroll
      for (int m4 = 0; m4 < 4; ++m4)
        #pragma unroll
        for (int n4 = 0; n4 < 4; ++n4)
          acc[m4][n4] = __builtin_amdgcn_mfma_f32_16x16x32_bf16(af[m4], bf[n4], acc[m4][n4], 0, 0, 0);
    }
    __syncthreads();
  }

  #pragma unroll
  for (int n4 = 0; n4 < 4; ++n4) {
    const int col = n0 + wc * 64 + n4 * 16 + lr;
    const float bias = bvec[col];
    #pragma unroll
    for (int m4 = 0; m4 < 4; ++m4) {
      const int row = m0 + wr * 64 + m4 * 16 + lk * 4;
      #pragma unroll
      for (int q = 0; q < 4; ++q)
        out[(size_t)(row + q) * 1024 + col] = acc[m4][n4][q] + bias;
    }
  }

  if (blockIdx.x == 0 && t == 0) {
    float dg = diag[0] + diag[1] + diag[3];
    if (dg != 0.0f) out[0] += dg;
  }
}

__global__ void signal_kernel(float* out, float val) { out[0] = val; }

// ---------------------------------------------------------------------------
extern "C" void kernel_launch(void* const* d_in, const int* in_sizes, int n_in,
                              void* d_out, int out_size, void* d_ws, size_t ws_size,
                              hipStream_t stream) {
  const float* x    = (const float*)d_in[0];
  const float* W    = (const float*)d_in[1];
  const float* bvec = (const float*)d_in[2];
  const float* vec  = (const float*)d_in[3];
  float* out = (float*)d_out;

  const size_t MB = 1024 * 1024;
  // layout: diag @0 (64B), hdr @256, ps0 @8192 (72KB), ps1 @98304 (72KB),
  //         Bh @1MB (2MB)
  const size_t need = 3 * MB;
  if (ws_size < need) {
    signal_kernel<<<1, 1, 0, stream>>>(out, 4.0e8f + (float)(ws_size >> 20) * 1000.0f);
    return;
  }
  float* diag = (float*)d_ws;
  int* hdr = (int*)((char*)d_ws + 256);
  uint4* ps0 = (uint4*)((char*)d_ws + 8192);
  uint4* ps1 = (uint4*)((char*)d_ws + 98304);
  unsigned short* Bh = (unsigned short*)((char*)d_ws + MB);

  hipMemsetAsync(diag, 0, 64, stream);
  gen_sched_kernel<<<2, 256, 0, stream>>>(ps0, ps1, hdr, diag);
  walk_kernel<<<64, 256, 0, stream>>>(ps0, ps1, hdr, W, vec, Bh, diag);
  gemm_kernel<<<2048, 256, 0, stream>>>(x, Bh, bvec, diag, out);
}

// Round 12
// 424.752 us; speedup vs baseline: 3.3733x; 1.0143x over previous
//
#include <hip/hip_runtime.h>

// ---------------------------------------------------------------------------
// KacLayer: out = x @ (W^T + M) + b, where M = A2 diag(vec) A1 (Kac walks).
// numpy default_rng(4048)/default_rng(4049): PCG64 + SeedSequence (subtractive
// mix) + 32-bit buffered Lemire ints (low u32 half first) — verified r7.
// r11: level-scheduled walk (verified). r12: GEMM traffic fixes —
// XCD-chunked block mapping (panel fetched once per XCD, consecutive bn) +
// LDS-bounce epilogue (float4 row writes; kills partial-line write inflate).
// ---------------------------------------------------------------------------

#define NSTEPS 3072
#define NCHUNK 26
#define NRAW (256 * NCHUNK)   // 6656 u64 (need 6144 + rejection slack)
#define MAXS 4608             // schedule slots per phase (3072 + pads)
#define MAXLEV 256

typedef __attribute__((ext_vector_type(8))) short short8;
typedef __attribute__((ext_vector_type(4))) float f32x4;

// ---------------- 128-bit PCG64 (numpy-exact) ------------------------------
struct U128 { unsigned long long lo, hi; };

__device__ __forceinline__ U128 mul128(U128 a, U128 b) {
  U128 r;
  r.lo = a.lo * b.lo;
  r.hi = __umul64hi(a.lo, b.lo) + a.lo * b.hi + a.hi * b.lo;
  return r;
}
__device__ __forceinline__ U128 add128(U128 a, U128 b) {
  U128 r; r.lo = a.lo + b.lo;
  r.hi = a.hi + b.hi + ((r.lo < a.lo) ? 1ull : 0ull);
  return r;
}
__device__ __forceinline__ U128 pcg_mult() {
  return U128{4865540595714422341ull, 2549297995355413924ull};
}
__device__ __forceinline__ U128 pcg_step(U128 st, U128 inc) {
  return add128(mul128(st, pcg_mult()), inc);
}
__device__ __forceinline__ unsigned long long pcg_out(U128 st) {
  unsigned long long x = st.hi ^ st.lo;
  unsigned int rot = (unsigned int)(st.hi >> 58);
  return (x >> rot) | (x << ((64u - rot) & 63u));
}

__device__ void pcg_seed(unsigned int seedval, U128* st, U128* inc) {
  unsigned int pool[4];
  unsigned int hc = 0x43b0d7e5u;                 // INIT_A
  auto hashmix = [&hc](unsigned int v) {
    v ^= hc; hc *= 0x931e8875u; v *= hc; v ^= v >> 16; return v;  // MULT_A
  };
  auto mixf = [](unsigned int x, unsigned int y) {
    unsigned int r = x * 0xca01f9ddu - y * 0x4973f715u;  // SUBTRACT (randutils)
    r ^= r >> 16; return r;
  };
  pool[0] = hashmix(seedval);
  pool[1] = hashmix(0u); pool[2] = hashmix(0u); pool[3] = hashmix(0u);
  for (int s = 0; s < 4; ++s)
    for (int d = 0; d < 4; ++d)
      if (s != d) pool[d] = mixf(pool[d], hashmix(pool[s]));
  unsigned int gc = 0x8b51f9ddu;                 // INIT_B
  unsigned int wv[8];
  for (int k = 0; k < 8; ++k) {
    unsigned int dv = pool[k & 3];
    dv ^= gc; gc *= 0x58f38dedu; dv *= gc; dv ^= dv >> 16;        // MULT_B
    wv[k] = dv;
  }
  unsigned long long o0 = (unsigned long long)wv[0] | ((unsigned long long)wv[1] << 32);
  unsigned long long o1 = (unsigned long long)wv[2] | ((unsigned long long)wv[3] << 32);
  unsigned long long o2 = (unsigned long long)wv[4] | ((unsigned long long)wv[5] << 32);
  unsigned long long o3 = (unsigned long long)wv[6] | ((unsigned long long)wv[7] << 32);
  U128 initstate = { o1, o0 };
  U128 initseq   = { o3, o2 };
  U128 icc; icc.lo = (initseq.lo << 1) | 1ull;
  icc.hi = (initseq.hi << 1) | (initseq.lo >> 63);
  *inc = icc;
  U128 s0 = {0ull, 0ull};
  s0 = pcg_step(s0, icc);
  s0 = add128(s0, initstate);
  s0 = pcg_step(s0, icc);
  *st = s0;
}

__device__ U128 pcg_advance(U128 st, U128 inc, unsigned long long delta) {
  U128 am = {1ull, 0ull}, ap = {0ull, 0ull};
  U128 cm = pcg_mult(), cp = inc;
  while (delta) {
    if (delta & 1ull) {
      am = mul128(am, cm);
      ap = add128(mul128(ap, cm), cp);
    }
    cp = mul128(add128(cm, U128{1ull, 0ull}), cp);
    cm = mul128(cm, cm);
    delta >>= 1;
  }
  return add128(mul128(st, am), ap);
}

__device__ __forceinline__ double first_draw(unsigned int seed) {
  U128 st, inc;
  pcg_seed(seed, &st, &inc);
  st = pcg_step(st, inc);
  return (double)(pcg_out(st) >> 11) * (1.0 / 9007199254740992.0);
}

__device__ __forceinline__ unsigned short f32_to_bf16(float f) {
  unsigned int u = __builtin_bit_cast(unsigned int, f);
  unsigned int r = u + 0x7fffu + ((u >> 16) & 1u);
  return (unsigned short)(r >> 16);
}

// ---------------- Kernel 1: schedule gen + level scheduling ----------------
__global__ __launch_bounds__(256) void gen_sched_kernel(uint4* __restrict__ ps0,
                                                        uint4* __restrict__ ps1,
                                                        int* __restrict__ hdr,
                                                        float* __restrict__ diag) {
  __shared__ unsigned long long raw[NRAW];          // 53 KB
  __shared__ unsigned int s_ij[NSTEPS];             // 12 KB
  __shared__ unsigned short s_list[2 * NSTEPS];     // 12 KB  (k<<1 | side)
  __shared__ short s_predA[NSTEPS];                 // 6 KB
  __shared__ short s_predB[NSTEPS];                 // 6 KB
  __shared__ unsigned short s_lev[NSTEPS];          // 6 KB
  __shared__ int s_cnt[1024];                       // 4 KB (also cursors)
  __shared__ int s_base[1025];                      // 4 KB
  __shared__ int s_lcnt[MAXLEV];                    // 1 KB (also cursors)
  __shared__ int s_lbase[MAXLEV];                   // 1 KB
  __shared__ int s_rej, s_p64, s_changed, s_maxlev, s_ns;
  const int w = blockIdx.x;     // walk: seed 4048 + w
  const int t = threadIdx.x;

  if (w == 0 && t == 0) {
    int m1 = first_draw(42u)    != 0.7739560485559633;
    int m2 = first_draw(0u)     != 0.6369616873214543;
    int m3 = first_draw(12345u) != 0.22733602246716966;
    if (m1 + m2 + m3 >= 2)
      diag[0] = 3.0e8f + (float)(m1 + 2 * m2 + 4 * m3) * 3.0e7f;
  }

  U128 st, inc;
  pcg_seed(4048u + (unsigned int)w, &st, &inc);
  U128 mine = pcg_advance(st, inc, (unsigned long long)t * NCHUNK);
  for (int q = 0; q < NCHUNK; ++q) {
    mine = pcg_step(mine, inc);
    raw[t * NCHUNK + q] = pcg_out(mine);
  }
  if (t == 0) { s_rej = 0; s_maxlev = 1; }
  __syncthreads();

  // u32 draw m: LOW half of u64 first, then HIGH (pcg64_next32 buffering)
  auto u32at = [&](int m) -> unsigned int {
    unsigned long long v = raw[m >> 1];
    return (m & 1) ? (unsigned int)(v >> 32) : (unsigned int)v;
  };

  for (int k = t; k < NSTEPS; k += 256) {
    unsigned long long m = (unsigned long long)u32at(NSTEPS + k) * 1023ull;
    if ((unsigned int)m < 4u) atomicAdd(&s_rej, 1);
  }
  __syncthreads();

  if (s_rej == 0) {
    for (int k = t; k < NSTEPS; k += 256) {
      unsigned int iv = u32at(k) >> 22;                 // (u32*1024)>>32
      unsigned long long m = (unsigned long long)u32at(NSTEPS + k) * 1023ull;
      unsigned int off = 1u + (unsigned int)(m >> 32);
      unsigned int jv = (iv + off) & 1023u;
      s_ij[k] = (iv << 16) | jv;
    }
    if (t == 0) s_p64 = NSTEPS;        // 6144 u32 consumed -> u64 idx 3072
  } else if (t == 0) {
    // exact sequential replay with rejections (P ~ 3e-6 per walk)
    int p = 0;
    for (int k = 0; k < NSTEPS; ++k) s_ij[k] = (u32at(p++) >> 22) << 16;
    for (int k = 0; k < NSTEPS; ++k) {
      unsigned long long m = (unsigned long long)u32at(p++) * 1023ull;
      unsigned int lo = (unsigned int)m;
      if (lo < 1023u) {
        while (lo < 4u) { m = (unsigned long long)u32at(p++) * 1023ull; lo = (unsigned int)m; }
      }
      unsigned int off = 1u + (unsigned int)(m >> 32);
      unsigned int iv = s_ij[k] >> 16;
      s_ij[k] = (iv << 16) | ((iv + off) & 1023u);
    }
    s_p64 = (p + 1) >> 1;
  }
  __syncthreads();

  // --- per-coord touch counts -> bases ---------------------------------
  for (int c = t; c < 1024; c += 256) s_cnt[c] = 0;
  __syncthreads();
  for (int k = t; k < NSTEPS; k += 256) {
    atomicAdd(&s_cnt[s_ij[k] >> 16], 1);
    atomicAdd(&s_cnt[s_ij[k] & 0xffffu], 1);
  }
  __syncthreads();
  if (t < 64) {
    int loc[16], tot = 0;
    #pragma unroll
    for (int q = 0; q < 16; ++q) { loc[q] = s_cnt[t * 16 + q]; tot += loc[q]; }
    int sc = tot;
    for (int off = 1; off < 64; off <<= 1) {
      int v = __shfl_up(sc, off);
      if (t >= off) sc += v;
    }
    int base = sc - tot;
    #pragma unroll
    for (int q = 0; q < 16; ++q) { s_base[t * 16 + q] = base; base += loc[q]; }
  }
  if (t == 0) s_base[1024] = 2 * NSTEPS;
  __syncthreads();

  // --- scatter (k,side) into buckets, sort, derive preds ----------------
  for (int c = t; c < 1024; c += 256) s_cnt[c] = 0;
  __syncthreads();
  for (int k = t; k < NSTEPS; k += 256) {
    unsigned int iv = s_ij[k] >> 16, jv = s_ij[k] & 0xffffu;
    int p1 = atomicAdd(&s_cnt[iv], 1);
    s_list[s_base[iv] + p1] = (unsigned short)(k << 1);
    int p2 = atomicAdd(&s_cnt[jv], 1);
    s_list[s_base[jv] + p2] = (unsigned short)((k << 1) | 1);
  }
  __syncthreads();
  for (int c = t; c < 1024; c += 256) {
    int b0 = s_base[c], b1 = s_base[c + 1];
    for (int a = b0 + 1; a < b1; ++a) {       // insertion sort (~6 elems)
      unsigned short v = s_list[a];
      int p = a;
      while (p > b0 && s_list[p - 1] > v) { s_list[p] = s_list[p - 1]; --p; }
      s_list[p] = v;
    }
    short prev = -1;
    for (int a = b0; a < b1; ++a) {
      int e = s_list[a]; int k = e >> 1;
      if (e & 1) s_predB[k] = prev; else s_predA[k] = prev;
      prev = (short)k;
    }
  }
  __syncthreads();

  // --- monotone relaxation to longest-path levels -----------------------
  for (int k = t; k < NSTEPS; k += 256) s_lev[k] = 1;
  __syncthreads();
  for (int it = 0; it < 300; ++it) {
    if (t == 0) s_changed = 0;
    __syncthreads();
    for (int k = t; k < NSTEPS; k += 256) {
      int la = s_predA[k] >= 0 ? (int)s_lev[s_predA[k]] : 0;
      int lb = s_predB[k] >= 0 ? (int)s_lev[s_predB[k]] : 0;
      int nl = 1 + (la > lb ? la : lb);
      if (nl > (int)s_lev[k]) {
        if (nl >= MAXLEV) { nl = MAXLEV - 1; diag[3] = 7.0e8f; }
        s_lev[k] = (unsigned short)nl; s_changed = 1;
      }
    }
    __syncthreads();
    int done = !s_changed;
    __syncthreads();
    if (done) break;
  }

  // --- histogram levels, padded bases (groups of 16) --------------------
  for (int L = t; L < MAXLEV; L += 256) s_lcnt[L] = 0;
  __syncthreads();
  for (int k = t; k < NSTEPS; k += 256) {
    atomicAdd(&s_lcnt[s_lev[k]], 1);
    atomicMax(&s_maxlev, (int)s_lev[k]);
  }
  __syncthreads();
  if (t == 0) {
    int run = 0;
    for (int L = 1; L <= s_maxlev; ++L) {
      s_lbase[L] = run;
      run += (s_lcnt[L] + 15) & ~15;
    }
    s_ns = run;
    hdr[w] = (run <= MAXS) ? run : MAXS;
    if (run > MAXS) diag[3] = 6.0e8f;
  }
  __syncthreads();
  const int ns = (s_ns <= MAXS) ? s_ns : MAXS;
  uint4* ps = w ? ps1 : ps0;
  uint4 noop;
  noop.x = (17408u << 16) | 17408u;   // scratch coord 1024 (*17)
  noop.y = __float_as_uint(1.0f);
  noop.z = __float_as_uint(0.0f);
  noop.w = 0u;
  for (int s = t; s < ns; s += 256) ps[s] = noop;
  for (int L = t; L < MAXLEV; L += 256) s_lcnt[L] = 0;   // reuse as cursors
  __syncthreads();
  const int base64 = s_p64;
  for (int k = t; k < NSTEPS; k += 256) {
    int lv = s_lev[k];
    int pos = atomicAdd(&s_lcnt[lv], 1);
    int slot = s_lbase[lv] + pos;
    if (slot < MAXS) {
      unsigned long long v = raw[base64 + k];
      double d = (double)(v >> 11) * (1.0 / 9007199254740992.0);
      double ang = d * 6.283185307179586;
      unsigned int ij = s_ij[k];
      unsigned int i17 = (ij >> 16) * 17u, j17 = (ij & 0xffffu) * 17u;
      uint4 ent;
      ent.x = (i17 << 16) | j17;
      ent.y = __float_as_uint((float)cos(ang));
      ent.z = __float_as_uint((float)sin(ang));
      ent.w = 0u;
      ps[slot] = ent;
    }
  }
}

// ---------------- Kernel 2: level-grouped Kac walk + combine ---------------
// L[c*17 + col]: 1025 coords (1024 = pad scratch), stride 17 breaks bank
// aliasing across the 4 sub-lanes. 64 lanes = 16 cols x 4 subs; each lane
// applies rotations {sub, sub+4, sub+8, sub+12} of each 16-disjoint group to
// its column. Cross-group ordering: same-wave in-order LDS.
__device__ void walk_groups(const uint4* __restrict__ SG, int ng,
                            float* __restrict__ L, int col, int sub) {
  if (ng <= 0) return;
  uint4 c0 = SG[sub], c1 = SG[sub + 4], c2 = SG[sub + 8], c3 = SG[sub + 12];
  for (int g = 0; g < ng; ++g) {
    const int nb = ((g + 1 < ng) ? (g + 1) : g) << 4;
    uint4 n0 = SG[nb + sub], n1 = SG[nb + sub + 4];
    uint4 n2 = SG[nb + sub + 8], n3 = SG[nb + sub + 12];
    const int i0 = (int)(c0.x >> 16) + col, j0 = (int)(c0.x & 0xffffu) + col;
    const int i1 = (int)(c1.x >> 16) + col, j1 = (int)(c1.x & 0xffffu) + col;
    const int i2 = (int)(c2.x >> 16) + col, j2 = (int)(c2.x & 0xffffu) + col;
    const int i3 = (int)(c3.x >> 16) + col, j3 = (int)(c3.x & 0xffffu) + col;
    float a0 = L[i0], b0 = L[j0], a1 = L[i1], b1 = L[j1];
    float a2 = L[i2], b2 = L[j2], a3 = L[i3], b3 = L[j3];
    const float p0 = __uint_as_float(c0.y), q0 = __uint_as_float(c0.z);
    const float p1 = __uint_as_float(c1.y), q1 = __uint_as_float(c1.z);
    const float p2 = __uint_as_float(c2.y), q2 = __uint_as_float(c2.z);
    const float p3 = __uint_as_float(c3.y), q3 = __uint_as_float(c3.z);
    L[i0] = fmaf(p0, a0, -q0 * b0); L[j0] = fmaf(q0, a0, p0 * b0);
    L[i1] = fmaf(p1, a1, -q1 * b1); L[j1] = fmaf(q1, a1, p1 * b1);
    L[i2] = fmaf(p2, a2, -q2 * b2); L[j2] = fmaf(q2, a2, p2 * b2);
    L[i3] = fmaf(p3, a3, -q3 * b3); L[j3] = fmaf(q3, a3, p3 * b3);
    c0 = n0; c1 = n1; c2 = n2; c3 = n3;
  }
}

__global__ __launch_bounds__(256) void walk_kernel(const uint4* __restrict__ ps0,
                                                   const uint4* __restrict__ ps1,
                                                   const int* __restrict__ hdr,
                                                   const float* __restrict__ W,
                                                   const float* __restrict__ vec,
                                                   unsigned short* __restrict__ Bh,
                                                   float* __restrict__ diag) {
  __shared__ float L[1025 * 17];     // 69.7 KB
  __shared__ uint4 SG[MAXS];         // 72 KB
  const int b = blockIdx.x;          // 0..63
  const int t = threadIdx.x;
  const int d0 = b * 16;
  int ns0 = hdr[0]; if (ns0 > MAXS) ns0 = MAXS;
  int ns1 = hdr[1]; if (ns1 > MAXS) ns1 = MAXS;

  for (int idx = t; idx < 1025 * 16; idx += 256) {
    int c = idx >> 4, col = idx & 15;
    L[c * 17 + col] = (c == d0 + col) ? 1.0f : 0.0f;
  }
  for (int s = t; s < ns0; s += 256) SG[s] = ps0[s];
  __syncthreads();
  if (t < 64) walk_groups(SG, ns0 >> 4, L, t & 15, t >> 4);
  __syncthreads();
  {  // Givens chains preserve unit norms
    bool bad = false;
    if (b == 0 && t < 16) {
      float ss = 0.0f;
      for (int c = 0; c < 1024; ++c) { float v = L[c * 17 + t]; ss += v * v; }
      bad = fabsf(ss - 1.0f) > 2.0e-3f;
    }
    unsigned long long bm = __ballot(bad);
    if (b == 0 && t == 0 && bm) diag[1] = 2.0e7f;
  }
  __syncthreads();
  for (int idx = t; idx < 1024 * 16; idx += 256) {
    int c = idx >> 4, col = idx & 15;
    L[c * 17 + col] *= vec[c];
  }
  for (int s = t; s < ns1; s += 256) SG[s] = ps1[s];
  __syncthreads();
  if (t < 64) walk_groups(SG, ns1 >> 4, L, t & 15, t >> 4);
  __syncthreads();
  // B[e][d0+dl] = W[e][d0+dl] + M[e][d0+dl];  M[e][d0+dl] = L[e*17+dl]
  const int dl = t & 15;
  const int eb = t >> 4;
  for (int p = 0; p < 64; ++p) {
    int e = eb + p * 16;
    Bh[e * 1024 + d0 + dl] = f32_to_bf16(W[e * 1024 + d0 + dl] + L[e * 17 + dl]);
  }
}

// ---------------- Kernel 3: bf16 GEMM out = x @ B^T + b --------------------
// XCD-chunked mapping: each XCD owns 32 bm panels; a panel's 8 bn-blocks run
// consecutively on that XCD -> x panel fetched once, then L2-hit.
// Epilogue: C staged through LDS (reusing A/B LDS) -> float4 row writes.
__device__ __forceinline__ int swz(int row, int colbyte) {
  return row * 128 + (colbyte ^ ((row & 7) << 4));
}

__global__ __launch_bounds__(256) void gemm_kernel(const float* __restrict__ x,
                                                   const unsigned short* __restrict__ Bhg,
                                                   const float* __restrict__ bvec,
                                                   const float* __restrict__ diag,
                                                   float* __restrict__ out) {
  __shared__ float smemf[64 * 132];          // 33.8 KB: A/B tiles, then C stage
  unsigned short* Ash = (unsigned short*)smemf;            // 16 KB
  unsigned short* Bsh = (unsigned short*)smemf + 128 * 64; // 16 KB
  float* Cst = smemf;                                      // reused post-loop
  const int t = threadIdx.x;
  const int bidx = blockIdx.x;
  const int xcd = bidx & 7;
  const int kk2 = bidx >> 3;
  const int bm = xcd * 32 + (kk2 >> 3);      // 0..255
  const int bn = kk2 & 7;                    // 0..7
  const int m0 = bm * 128, n0 = bn * 128;
  const int l = t & 63, w = t >> 6;
  const int wr = w >> 1, wc = w & 1;
  const int lr = l & 15, lk = l >> 4;
  const int arb = t >> 4, akb = (t & 15) << 3;
  const int brb = t >> 3, bkb = (t & 7) << 4;

  f32x4 acc[4][4] = {};
  float4 ra[8];
  uint4 rb[4];

  #pragma unroll
  for (int p = 0; p < 8; ++p)
    ra[p] = *(const float4*)&x[(size_t)(m0 + arb + p * 16) * 1024 + (akb >> 1)];
  #pragma unroll
  for (int p = 0; p < 4; ++p)
    rb[p] = *(const uint4*)&Bhg[(size_t)(n0 + brb + p * 32) * 1024 + (bkb >> 1)];

  for (int kt = 0; kt < 16; ++kt) {
    #pragma unroll
    for (int p = 0; p < 8; ++p) {
      ushort4 hv;
      hv.x = f32_to_bf16(ra[p].x); hv.y = f32_to_bf16(ra[p].y);
      hv.z = f32_to_bf16(ra[p].z); hv.w = f32_to_bf16(ra[p].w);
      *(ushort4*)((char*)Ash + swz(arb + p * 16, akb)) = hv;
    }
    #pragma unroll
    for (int p = 0; p < 4; ++p)
      *(uint4*)((char*)Bsh + swz(brb + p * 32, bkb)) = rb[p];
    __syncthreads();

    if (kt + 1 < 16) {
      const int k0 = (kt + 1) * 64;
      #pragma unroll
      for (int p = 0; p < 8; ++p)
        ra[p] = *(const float4*)&x[(size_t)(m0 + arb + p * 16) * 1024 + k0 + (akb >> 1)];
      #pragma unroll
      for (int p = 0; p < 4; ++p)
        rb[p] = *(const uint4*)&Bhg[(size_t)(n0 + brb + p * 32) * 1024 + k0 + (bkb >> 1)];
    }

    #pragma unroll
    for (int kk = 0; kk < 64; kk += 32) {
      short8 af[4], bf[4];
      const int cb = kk * 2 + lk * 16;
      #pragma unroll
      for (int m4 = 0; m4 < 4; ++m4)
        af[m4] = *(const short8*)((const char*)Ash + swz(wr * 64 + m4 * 16 + lr, cb));
      #pragma unroll
      for (int n4 = 0; n4 < 4; ++n4)
        bf[n4] = *(const short8*)((const char*)Bsh + swz(wc * 64 + n4 * 16 + lr, cb));
      #pragma unroll
      for (int m4 = 0; m4 < 4; ++m4)
        #pragma unroll
        for (int n4 = 0; n4 < 4; ++n4)
          acc[m4][n4] = __builtin_amdgcn_mfma_f32_16x16x32_bf16(af[m4], bf[n4], acc[m4][n4], 0, 0, 0);
    }
    __syncthreads();
  }

  // ---- epilogue: two 64-row halves staged through LDS, float4 row writes --
  #pragma unroll
  for (int half = 0; half < 2; ++half) {
    if (wr == half) {
      #pragma unroll
      for (int n4 = 0; n4 < 4; ++n4) {
        const int col = wc * 64 + n4 * 16 + lr;
        const float bias = bvec[n0 + col];
        #pragma unroll
        for (int m4 = 0; m4 < 4; ++m4)
          #pragma unroll
          for (int q = 0; q < 4; ++q)
            Cst[(m4 * 16 + lk * 4 + q) * 132 + col] = acc[m4][n4][q] + bias;
      }
    }
    __syncthreads();
    {
      const int rg = t >> 5;            // 0..7
      const int c4 = (t & 31) * 4;
      #pragma unroll
      for (int rr = 0; rr < 8; ++rr) {
        int r = rg * 8 + rr;
        float4 v = *(const float4*)&Cst[r * 132 + c4];
        *(float4*)&out[(size_t)(m0 + half * 64 + r) * 1024 + (n0 + c4)] = v;
      }
    }
    __syncthreads();
  }

  if (bidx == 0 && t == 0) {
    float dg = diag[0] + diag[1] + diag[3];
    if (dg != 0.0f) out[0] += dg;
  }
}

__global__ void signal_kernel(float* out, float val) { out[0] = val; }

// ---------------------------------------------------------------------------
extern "C" void kernel_launch(void* const* d_in, const int* in_sizes, int n_in,
                              void* d_out, int out_size, void* d_ws, size_t ws_size,
                              hipStream_t stream) {
  const float* x    = (const float*)d_in[0];
  const float* W    = (const float*)d_in[1];
  const float* bvec = (const float*)d_in[2];
  const float* vec  = (const float*)d_in[3];
  float* out = (float*)d_out;

  const size_t MB = 1024 * 1024;
  // layout: diag @0 (64B), hdr @256, ps0 @8192 (72KB), ps1 @98304 (72KB),
  //         Bh @1MB (2MB)
  const size_t need = 3 * MB;
  if (ws_size < need) {
    signal_kernel<<<1, 1, 0, stream>>>(out, 4.0e8f + (float)(ws_size >> 20) * 1000.0f);
    return;
  }
  float* diag = (float*)d_ws;
  int* hdr = (int*)((char*)d_ws + 256);
  uint4* ps0 = (uint4*)((char*)d_ws + 8192);
  uint4* ps1 = (uint4*)((char*)d_ws + 98304);
  unsigned short* Bh = (unsigned short*)((char*)d_ws + MB);

  hipMemsetAsync(diag, 0, 64, stream);
  gen_sched_kernel<<<2, 256, 0, stream>>>(ps0, ps1, hdr, diag);
  walk_kernel<<<64, 256, 0, stream>>>(ps0, ps1, hdr, W, vec, Bh, diag);
  gemm_kernel<<<2048, 256, 0, stream>>>(x, Bh, bvec, diag, out);
}